// Round 2
// baseline (1877.681 us; speedup 1.0000x reference)
//
#include <hip/hip_runtime.h>

#define B_ 128
#define L_ 64
#define V_ 8192
#define E_ 128
#define H_ 128
#define G4_ 512
#define NROW (B_*L_)

__device__ __forceinline__ float sigm(float x){ return 1.f/(1.f + __expf(-x)); }

// ---------------------------------------------------------------- transpose W_visit [E,V] -> WT [V,E]
__global__ __launch_bounds__(256) void k_transpose_wv(const float* __restrict__ Wv, float* __restrict__ WT){
    __shared__ float tile[16][129];
    int v0 = blockIdx.x * 16;
    int t = threadIdx.x;
    #pragma unroll
    for(int i=0;i<8;i++){
        int idx = i*256 + t; int e = idx >> 4; int vv = idx & 15;
        tile[vv][e] = Wv[(size_t)e*V_ + v0 + vv];
    }
    __syncthreads();
    #pragma unroll
    for(int i=0;i<8;i++){
        int idx = i*256 + t; int vv = idx >> 7; int e = idx & 127;
        WT[(size_t)(v0+vv)*E_ + e] = tile[vv][e];
    }
}

// ---------------------------------------------------------------- v = (x @ Wv^T + bin_embed[delta]) * m
__global__ __launch_bounds__(256) void k_visit_embed(const float* __restrict__ px, const float* __restrict__ vmask,
                                                     const int* __restrict__ bins, const float* __restrict__ bemb,
                                                     const float* __restrict__ WT, float* __restrict__ v){
    __shared__ int idxs[512];
    __shared__ int cnt;
    __shared__ int dsh;
    __shared__ float msh;
    int row = blockIdx.x; int l = row & 63;
    int t = threadIdx.x;
    if(t==0){
        cnt = 0;
        float m = vmask[row];
        int d = 0;
        if(l > 0){ d = bins[row] - bins[row-1]; d = d < 0 ? 0 : (d > 513 ? 513 : d); }
        if(!(m > 0.f)) d = 0;
        dsh = d; msh = m;
    }
    __syncthreads();
    const uint4* xr4 = (const uint4*)(px + (size_t)row * V_);
    for(int i=t;i<2048;i+=256){
        uint4 u = xr4[i];
        unsigned int w[4] = {u.x,u.y,u.z,u.w};
        #pragma unroll
        for(int j=0;j<4;j++){
            if(w[j]){ int p = atomicAdd(&cnt,1); if(p<512) idxs[p] = i*4 + j; }
        }
    }
    __syncthreads();
    int n = cnt; if(n > 512) n = 512;
    float m = msh;
    if(t < 128){
        float acc = bemb[dsh*E_ + t];
        for(int j=0;j<n;j++) acc += WT[(size_t)idxs[j]*E_ + t];
        v[(size_t)row*E_ + t] = acc * m;
    }
}

// ---------------------------------------------------------------- xg = A @ W_ih^T + b_ih + b_hh   (A fp32 [8192,128])
__global__ __launch_bounds__(256) void k_gemm_xg(const float* __restrict__ A, const float* __restrict__ Wih,
                                                 const float* __restrict__ bih, const float* __restrict__ bhh,
                                                 float* __restrict__ xg){
    __shared__ float at[128][20];
    int row0 = blockIdx.x * 16;
    int t = threadIdx.x;
    #pragma unroll
    for(int i=0;i<8;i++){
        int idx = i*256 + t; int n = idx >> 7; int e = idx & 127;
        at[e][n] = A[(size_t)(row0+n)*E_ + e];
    }
    __syncthreads();
    int g0 = t, g1 = t + 256;
    float acc0[16], acc1[16];
    #pragma unroll
    for(int n=0;n<16;n++){ acc0[n]=0.f; acc1[n]=0.f; }
    for(int e=0;e<128;e++){
        float w0 = Wih[g0*E_ + e];
        float w1 = Wih[g1*E_ + e];
        const float4* ap = (const float4*)&at[e][0];
        float4 A0=ap[0], A1=ap[1], A2=ap[2], A3=ap[3];
        float av[16] = {A0.x,A0.y,A0.z,A0.w,A1.x,A1.y,A1.z,A1.w,
                        A2.x,A2.y,A2.z,A2.w,A3.x,A3.y,A3.z,A3.w};
        #pragma unroll
        for(int n=0;n<16;n++){ acc0[n] += av[n]*w0; acc1[n] += av[n]*w1; }
    }
    float bb0 = bih[g0] + bhh[g0];
    float bb1 = bih[g1] + bhh[g1];
    #pragma unroll
    for(int n=0;n<16;n++){
        xg[(size_t)(row0+n)*G4_ + g0] = acc0[n] + bb0;
        xg[(size_t)(row0+n)*G4_ + g1] = acc1[n] + bb1;
    }
}

// ---------------------------------------------------------------- LSTM: 4 batch rows per block, loop over L
__global__ __launch_bounds__(256) void k_lstm(const float* __restrict__ xg, const float* __restrict__ Whh,
                                              const float* __restrict__ vmask, float* __restrict__ hout){
    __shared__ float hst[128][4];  // [e][r] raw (unmasked) h
    __shared__ float cst[128][4];
    __shared__ float gs[4][512];
    int b0 = blockIdx.x * 4;
    int t = threadIdx.x;
    for(int i=t;i<512;i+=256){ ((float*)hst)[i] = 0.f; ((float*)cst)[i] = 0.f; }
    __syncthreads();
    int g0 = t, g1 = t + 256;
    for(int l=0;l<64;l++){
        float acc0[4], acc1[4];
        #pragma unroll
        for(int r=0;r<4;r++){ acc0[r]=0.f; acc1[r]=0.f; }
        for(int e=0;e<128;e++){
            float w0 = Whh[g0*H_ + e];
            float w1 = Whh[g1*H_ + e];
            const float4* hp4 = (const float4*)&hst[e][0];
            float4 hv4 = hp4[0];
            float hv[4] = {hv4.x, hv4.y, hv4.z, hv4.w};
            #pragma unroll
            for(int r=0;r<4;r++){ acc0[r] += hv[r]*w0; acc1[r] += hv[r]*w1; }
        }
        #pragma unroll
        for(int r=0;r<4;r++){
            gs[r][g0] = acc0[r] + xg[(size_t)((b0+r)*64 + l)*G4_ + g0];
            gs[r][g1] = acc1[r] + xg[(size_t)((b0+r)*64 + l)*G4_ + g1];
        }
        __syncthreads();
        {
            int j = t & 127; int half = t >> 7;
            #pragma unroll
            for(int rr=0;rr<2;rr++){
                int r = half*2 + rr;
                float gi = gs[r][j], gf = gs[r][j+128], gg = gs[r][j+256], go = gs[r][j+384];
                float c = cst[j][r];
                c = sigm(gf)*c + sigm(gi)*tanhf(gg);
                float h = sigm(go)*tanhf(c);
                cst[j][r] = c; hst[j][r] = h;
                float m = vmask[(b0+r)*64 + l];
                hout[(size_t)((b0+r)*64 + l)*H_ + j] = h * m;
            }
        }
        __syncthreads();
    }
}

// ---------------------------------------------------------------- hp = (h_prev @ W_proj^T) * m
__global__ __launch_bounds__(256) void k_hp(const float* __restrict__ h, const float* __restrict__ Wproj,
                                            const float* __restrict__ vmask, float* __restrict__ hp){
    __shared__ float at[128][20];
    int row0 = blockIdx.x * 16;
    int t = threadIdx.x;
    #pragma unroll
    for(int i=0;i<8;i++){
        int idx = i*256 + t; int n = idx >> 7; int e = idx & 127;
        int r = row0 + n;
        at[e][n] = (r & 63) ? h[(size_t)(r-1)*H_ + e] : 0.f;
    }
    __syncthreads();
    int j = t & 127; int half = t >> 7;
    float acc[8];
    #pragma unroll
    for(int r=0;r<8;r++) acc[r]=0.f;
    for(int e=0;e<128;e++){
        float w = Wproj[j*H_ + e];
        const float4* ap = (const float4*)&at[e][half*8];
        float4 A0=ap[0], A1=ap[1];
        float av[8] = {A0.x,A0.y,A0.z,A0.w,A1.x,A1.y,A1.z,A1.w};
        #pragma unroll
        for(int r=0;r<8;r++) acc[r] += av[r]*w;
    }
    #pragma unroll
    for(int r=0;r<8;r++){
        int row = row0 + half*8 + r;
        hp[(size_t)row*E_ + j] = acc[r] * vmask[row];
    }
}

// ---------------------------------------------------------------- logits = h[b, len-1] . W_cls + b_cls
__global__ void k_logits(const float* __restrict__ h, const float* __restrict__ vmask,
                         const float* __restrict__ Wcls, const float* __restrict__ bcls, float* __restrict__ out){
    int b = blockIdx.x; int t = threadIdx.x; // 64 threads (1 wave)
    float s = vmask[b*64 + t];
    #pragma unroll
    for(int off=32;off;off>>=1) s += __shfl_down(s, off);
    s = __shfl(s, 0);
    int len = (int)(s + 0.5f); if(len < 1) len = 1;
    const float* hr = h + (size_t)(b*64 + len - 1)*H_;
    float val = hr[t]*Wcls[t] + hr[t+64]*Wcls[t+64];
    #pragma unroll
    for(int off=32;off;off>>=1) val += __shfl_down(val, off);
    if(t==0) out[b] = val + bcls[0];
}

// ---------------------------------------------------------------- diffusion loss (single fuse_eps on z_t)
__global__ __launch_bounds__(256) void k_diff_loss(const float* __restrict__ v, const float* __restrict__ hp,
        const float* __restrict__ eps, const int* __restrict__ tdiff, const float* __restrict__ vmask,
        const float* __restrict__ temb, const float* __restrict__ Wf, const float* __restrict__ bfu,
        const float* __restrict__ We1, const float* __restrict__ be1,
        const float* __restrict__ We2, const float* __restrict__ be2, float* __restrict__ lossacc){
    __shared__ float zs[16][128], hps[16][128];
    __shared__ float xt[256][20], y1t[128][20];
    __shared__ float ssh[16][2], ash[16][2];
    __shared__ float mrow[16]; __shared__ int trow[16];
    __shared__ float sabar[10];
    __shared__ float rb[4];
    int row0 = blockIdx.x * 16; int t = threadIdx.x;
    if(t==0){
        float p = 1.f;
        for(int k=0;k<10;k++){ float b = 1e-4f + (0.02f - 1e-4f)*k/9.f; p *= (1.f - b); sabar[k] = p; }
    }
    if(t < 16){
        int row = row0 + t; float m = vmask[row];
        mrow[t] = m; trow[t] = (m > 0.f) ? tdiff[row >> 6] : 1;
    }
    __syncthreads();
    #pragma unroll
    for(int i=0;i<8;i++){
        int idx = i*256 + t; int r = idx >> 7; int e = idx & 127; int row = row0 + r;
        float ab = sabar[trow[r]-1];
        float zt = (sqrtf(ab)*v[(size_t)row*E_ + e] + sqrtf(1.f - ab)*eps[(size_t)row*E_ + e]) * mrow[r];
        zs[r][e] = zt;
        hps[r][e] = hp[(size_t)row*E_ + e];
    }
    __syncthreads();
    // fuse gate logits
    if(t < 32){
        int r = t >> 1, k = t & 1;
        float s = bfu[k];
        for(int e=0;e<128;e++) s += zs[r][e]*Wf[k*256 + e];
        for(int e=0;e<128;e++) s += hps[r][e]*Wf[k*256 + 128 + e];
        ssh[r][k] = s;
    }
    __syncthreads();
    if(t < 16){
        float s0 = ssh[t][0], s1 = ssh[t][1];
        float mx = fmaxf(s0,s1);
        float e0 = __expf(s0-mx), e1 = __expf(s1-mx);
        float inv = 1.f/(e0+e1);
        ash[t][0] = e0*inv; ash[t][1] = e1*inv;
    }
    __syncthreads();
    // build x^T
    {
        int e = t;
        if(e < 128){
            #pragma unroll
            for(int r=0;r<16;r++) xt[e][r] = ash[r][0]*zs[r][e] + ash[r][1]*hps[r][e];
        } else {
            int e2 = e - 128;
            #pragma unroll
            for(int r=0;r<16;r++) xt[e][r] = temb[trow[r]*E_ + e2];
        }
    }
    __syncthreads();
    int j = t & 127, half = t >> 7;
    // y1 = relu(x @ We1^T + be1)
    {
        float acc[8]; float bb = be1[j];
        #pragma unroll
        for(int r=0;r<8;r++) acc[r] = bb;
        for(int e=0;e<256;e++){
            float w = We1[j*256 + e];
            const float4* xp = (const float4*)&xt[e][half*8];
            float4 X0=xp[0], X1=xp[1];
            float xv[8] = {X0.x,X0.y,X0.z,X0.w,X1.x,X1.y,X1.z,X1.w};
            #pragma unroll
            for(int r=0;r<8;r++) acc[r] += xv[r]*w;
        }
        #pragma unroll
        for(int r=0;r<8;r++) y1t[j][half*8 + r] = fmaxf(acc[r], 0.f);
    }
    __syncthreads();
    // y = y1 @ We2^T + be2 ; loss
    float acc2[8];
    {
        float bb = be2[j];
        #pragma unroll
        for(int r=0;r<8;r++) acc2[r] = bb;
        for(int e=0;e<128;e++){
            float w = We2[j*128 + e];
            const float4* yp = (const float4*)&y1t[e][half*8];
            float4 Y0=yp[0], Y1=yp[1];
            float yv[8] = {Y0.x,Y0.y,Y0.z,Y0.w,Y1.x,Y1.y,Y1.z,Y1.w};
            #pragma unroll
            for(int r=0;r<8;r++) acc2[r] += yv[r]*w;
        }
    }
    float lp = 0.f;
    #pragma unroll
    for(int r=0;r<8;r++){
        int rr = half*8 + r; int row = row0 + rr;
        float d = acc2[r] - eps[(size_t)row*E_ + j];
        lp += d*d*mrow[rr];
    }
    #pragma unroll
    for(int off=32;off;off>>=1) lp += __shfl_down(lp, off);
    if((t & 63) == 0) rb[t >> 6] = lp;
    __syncthreads();
    if(t == 0) atomicAdd(lossacc, rb[0]+rb[1]+rb[2]+rb[3]);
}

// ---------------------------------------------------------------- reverse diffusion: 10 fuse_eps steps in-kernel
__global__ __launch_bounds__(256) void k_reverse(const float* __restrict__ hp, const float* __restrict__ z0,
        const float* __restrict__ noise, const float* __restrict__ vmask, const float* __restrict__ temb,
        const float* __restrict__ Wf, const float* __restrict__ bfu,
        const float* __restrict__ We1, const float* __restrict__ be1,
        const float* __restrict__ We2, const float* __restrict__ be2, float* __restrict__ vsyn){
    __shared__ float zs[16][128], hps[16][128];
    __shared__ float xt[256][20], y1t[128][20];
    __shared__ float ssh[16][2], ash[16][2];
    __shared__ float mrow[16];
    __shared__ float sbeta[10], sabar[10];
    int row0 = blockIdx.x * 16; int t = threadIdx.x;
    if(t==0){
        float p = 1.f;
        for(int k=0;k<10;k++){ float b = 1e-4f + (0.02f - 1e-4f)*k/9.f; sbeta[k] = b; p *= (1.f - b); sabar[k] = p; }
    }
    if(t < 16) mrow[t] = vmask[row0 + t];
    __syncthreads();
    #pragma unroll
    for(int i=0;i<8;i++){
        int idx = i*256 + t; int r = idx >> 7; int e = idx & 127; int row = row0 + r;
        zs[r][e] = z0[(size_t)row*E_ + e];
        hps[r][e] = hp[(size_t)row*E_ + e];
    }
    __syncthreads();
    int j = t & 127, half = t >> 7;
    for(int s=0;s<10;s++){
        int kk = 10 - s;
        if(t < 32){
            int r = t >> 1, k = t & 1;
            float sv = bfu[k];
            for(int e=0;e<128;e++) sv += zs[r][e]*Wf[k*256 + e];
            for(int e=0;e<128;e++) sv += hps[r][e]*Wf[k*256 + 128 + e];
            ssh[r][k] = sv;
        }
        __syncthreads();
        if(t < 16){
            float s0 = ssh[t][0], s1 = ssh[t][1];
            float mx = fmaxf(s0,s1);
            float e0 = __expf(s0-mx), e1 = __expf(s1-mx);
            float inv = 1.f/(e0+e1);
            ash[t][0] = e0*inv; ash[t][1] = e1*inv;
        }
        __syncthreads();
        {
            int e = t;
            if(e < 128){
                #pragma unroll
                for(int r=0;r<16;r++) xt[e][r] = ash[r][0]*zs[r][e] + ash[r][1]*hps[r][e];
            } else {
                int e2 = e - 128;
                #pragma unroll
                for(int r=0;r<16;r++){
                    int tt = (mrow[r] > 0.f) ? kk : 1;
                    xt[e][r] = temb[tt*E_ + e2];
                }
            }
        }
        __syncthreads();
        float acc[8]; float bb = be1[j];
        #pragma unroll
        for(int r=0;r<8;r++) acc[r] = bb;
        for(int e=0;e<256;e++){
            float w = We1[j*256 + e];
            const float4* xp = (const float4*)&xt[e][half*8];
            float4 X0=xp[0], X1=xp[1];
            float xv[8] = {X0.x,X0.y,X0.z,X0.w,X1.x,X1.y,X1.z,X1.w};
            #pragma unroll
            for(int r=0;r<8;r++) acc[r] += xv[r]*w;
        }
        #pragma unroll
        for(int r=0;r<8;r++) y1t[j][half*8 + r] = fmaxf(acc[r], 0.f);
        __syncthreads();
        float acc2[8]; float bb2 = be2[j];
        #pragma unroll
        for(int r=0;r<8;r++) acc2[r] = bb2;
        for(int e=0;e<128;e++){
            float w = We2[j*128 + e];
            const float4* yp = (const float4*)&y1t[e][half*8];
            float4 Y0=yp[0], Y1=yp[1];
            float yv[8] = {Y0.x,Y0.y,Y0.z,Y0.w,Y1.x,Y1.y,Y1.z,Y1.w};
            #pragma unroll
            for(int r=0;r<8;r++) acc2[r] += yv[r]*w;
        }
        float beta = sbeta[kk-1];
        float c1 = beta / sqrtf(1.f - sabar[kk-1]);
        float c2 = 1.f / sqrtf(1.f - beta);
        float sb = sqrtf(beta);
        #pragma unroll
        for(int r=0;r<8;r++){
            int rr = half*8 + r; int row = row0 + rr;
            float z = zs[rr][j];
            float mean = (z - c1*acc2[r]) * c2;
            float nz = noise[((size_t)s*NROW + row)*E_ + j];
            float znew = (kk > 1) ? (mean + sb*nz) : mean;
            zs[rr][j] = znew * mrow[rr];
        }
        __syncthreads();
    }
    #pragma unroll
    for(int i=0;i<8;i++){
        int idx = i*256 + t; int r = idx >> 7; int e = idx & 127;
        vsyn[(size_t)(row0+r)*E_ + e] = zs[r][e];
    }
}

// ---------------------------------------------------------------- loss finalize
__global__ void k_finalize(const float* __restrict__ lossacc, const float* __restrict__ vmask, float* __restrict__ out){
    __shared__ float rb[4];
    int t = threadIdx.x;
    float s = 0.f;
    for(int i=t;i<NROW;i+=256) s += vmask[i];
    #pragma unroll
    for(int off=32;off;off>>=1) s += __shfl_down(s, off);
    if((t & 63) == 0) rb[t >> 6] = s;
    __syncthreads();
    if(t == 0){
        float denom = rb[0]+rb[1]+rb[2]+rb[3];
        if(denom < 1.f) denom = 1.f;
        out[256] = lossacc[0] / denom;
    }
}

extern "C" void kernel_launch(void* const* d_in, const int* in_sizes, int n_in,
                              void* d_out, int out_size, void* d_ws, size_t ws_size,
                              hipStream_t stream){
    const float* px    = (const float*)d_in[0];
    const float* vmask = (const float*)d_in[1];
    const int*   bins  = (const int*)d_in[2];
    const int*   tdiff = (const int*)d_in[3];
    const float* eps   = (const float*)d_in[4];
    const float* z0    = (const float*)d_in[5];
    const float* noise = (const float*)d_in[6];
    const float* Wv    = (const float*)d_in[7];
    const float* bemb  = (const float*)d_in[8];
    const float* Wih   = (const float*)d_in[9];
    const float* Whh   = (const float*)d_in[10];
    const float* bih   = (const float*)d_in[11];
    const float* bhh   = (const float*)d_in[12];
    const float* Wcls  = (const float*)d_in[13];
    const float* bcls  = (const float*)d_in[14];
    const float* Wproj = (const float*)d_in[15];
    const float* temb  = (const float*)d_in[16];
    const float* Wf    = (const float*)d_in[17];
    const float* bfu   = (const float*)d_in[18];
    const float* We1   = (const float*)d_in[19];
    const float* be1   = (const float*)d_in[20];
    const float* We2   = (const float*)d_in[21];
    const float* be2   = (const float*)d_in[22];
    float* out = (float*)d_out;

    float* ws      = (float*)d_ws;
    float* WT      = ws;                 // 8192*128 = 1,048,576
    float* v       = ws + 1048576;       // 1,048,576
    float* xg      = ws + 2097152;       // 8192*512 = 4,194,304
    float* h       = ws + 6291456;       // 1,048,576
    float* hp      = ws + 7340032;       // 1,048,576
    float* vsyn    = ws + 8388608;       // 1,048,576
    float* lossacc = ws + 9437184;       // 1

    hipLaunchKernelGGL(k_transpose_wv, dim3(V_/16), dim3(256), 0, stream, Wv, WT);
    hipLaunchKernelGGL(k_visit_embed, dim3(NROW), dim3(256), 0, stream, px, vmask, bins, bemb, WT, v);
    hipLaunchKernelGGL(k_gemm_xg, dim3(NROW/16), dim3(256), 0, stream, v, Wih, bih, bhh, xg);
    hipLaunchKernelGGL(k_lstm, dim3(B_/4), dim3(256), 0, stream, xg, Whh, vmask, h);
    hipLaunchKernelGGL(k_logits, dim3(B_), dim3(64), 0, stream, h, vmask, Wcls, bcls, out);
    hipLaunchKernelGGL(k_hp, dim3(NROW/16), dim3(256), 0, stream, h, Wproj, vmask, hp);
    hipMemsetAsync(lossacc, 0, sizeof(float), stream);
    hipLaunchKernelGGL(k_diff_loss, dim3(NROW/16), dim3(256), 0, stream,
                       v, hp, eps, tdiff, vmask, temb, Wf, bfu, We1, be1, We2, be2, lossacc);
    hipLaunchKernelGGL(k_reverse, dim3(NROW/16), dim3(256), 0, stream,
                       hp, z0, noise, vmask, temb, Wf, bfu, We1, be1, We2, be2, vsyn);
    hipLaunchKernelGGL(k_gemm_xg, dim3(NROW/16), dim3(256), 0, stream, vsyn, Wih, bih, bhh, xg);
    hipLaunchKernelGGL(k_lstm, dim3(B_/4), dim3(256), 0, stream, xg, Whh, vmask, h);
    hipLaunchKernelGGL(k_logits, dim3(B_), dim3(64), 0, stream, h, vmask, Wcls, bcls, out + 128);
    hipLaunchKernelGGL(k_finalize, dim3(1), dim3(256), 0, stream, lossacc, vmask, out);
}

// Round 3
// 1184.695 us; speedup vs baseline: 1.5849x; 1.5849x over previous
//
#include <hip/hip_runtime.h>

#define B_ 128
#define L_ 64
#define V_ 8192
#define E_ 128
#define H_ 128
#define G4_ 512
#define NROW (B_*L_)
#define HSTRIDE 136

typedef unsigned short u16;
typedef __attribute__((ext_vector_type(8))) short bf16x8;
typedef __attribute__((ext_vector_type(4))) float f32x4;

__device__ __forceinline__ float sigm(float x){ return 1.f/(1.f + __expf(-x)); }
__device__ __forceinline__ u16 f2bf(float f){
    union { unsigned int i; float f; } x; x.f = f;
    unsigned int r = x.i + 0x7fff + ((x.i >> 16) & 1);
    return (u16)(r >> 16);
}

// ---------------------------------------------------------------- transpose W_visit [E,V] -> WT [V,E]
__global__ __launch_bounds__(256) void k_transpose_wv(const float* __restrict__ Wv, float* __restrict__ WT){
    __shared__ float tile[16][129];
    int v0 = blockIdx.x * 16;
    int t = threadIdx.x;
    #pragma unroll
    for(int i=0;i<8;i++){
        int idx = i*256 + t; int e = idx >> 4; int vv = idx & 15;
        tile[vv][e] = Wv[(size_t)e*V_ + v0 + vv];
    }
    __syncthreads();
    #pragma unroll
    for(int i=0;i<8;i++){
        int idx = i*256 + t; int vv = idx >> 7; int e = idx & 127;
        WT[(size_t)(v0+vv)*E_ + e] = tile[vv][e];
    }
}

// ---------------------------------------------------------------- v = (x @ Wv^T + bin_embed[delta]) * m
__global__ __launch_bounds__(256) void k_visit_embed(const float* __restrict__ px, const float* __restrict__ vmask,
                                                     const int* __restrict__ bins, const float* __restrict__ bemb,
                                                     const float* __restrict__ WT, float* __restrict__ v){
    __shared__ int idxs[512];
    __shared__ int cnt;
    __shared__ int dsh;
    __shared__ float msh;
    int row = blockIdx.x; int l = row & 63;
    int t = threadIdx.x;
    if(t==0){
        cnt = 0;
        float m = vmask[row];
        int d = 0;
        if(l > 0){ d = bins[row] - bins[row-1]; d = d < 0 ? 0 : (d > 513 ? 513 : d); }
        if(!(m > 0.f)) d = 0;
        dsh = d; msh = m;
    }
    __syncthreads();
    const uint4* xr4 = (const uint4*)(px + (size_t)row * V_);
    for(int i=t;i<2048;i+=256){
        uint4 u = xr4[i];
        unsigned int w[4] = {u.x,u.y,u.z,u.w};
        #pragma unroll
        for(int j=0;j<4;j++){
            if(w[j]){ int p = atomicAdd(&cnt,1); if(p<512) idxs[p] = i*4 + j; }
        }
    }
    __syncthreads();
    int n = cnt; if(n > 512) n = 512;
    float m = msh;
    if(t < 128){
        float acc = bemb[dsh*E_ + t];
        for(int j=0;j<n;j++) acc += WT[(size_t)idxs[j]*E_ + t];
        v[(size_t)row*E_ + t] = acc * m;
    }
}

// ---------------------------------------------------------------- xg = A @ W_ih^T + b_ih + b_hh   (A fp32 [8192,128])
__global__ __launch_bounds__(256) void k_gemm_xg(const float* __restrict__ A, const float* __restrict__ Wih,
                                                 const float* __restrict__ bih, const float* __restrict__ bhh,
                                                 float* __restrict__ xg){
    __shared__ float at[128][20];
    int row0 = blockIdx.x * 16;
    int t = threadIdx.x;
    #pragma unroll
    for(int i=0;i<8;i++){
        int idx = i*256 + t; int n = idx >> 7; int e = idx & 127;
        at[e][n] = A[(size_t)(row0+n)*E_ + e];
    }
    __syncthreads();
    int g0 = t, g1 = t + 256;
    float acc0[16], acc1[16];
    #pragma unroll
    for(int n=0;n<16;n++){ acc0[n]=0.f; acc1[n]=0.f; }
    for(int e=0;e<128;e++){
        float w0 = Wih[g0*E_ + e];
        float w1 = Wih[g1*E_ + e];
        const float4* ap = (const float4*)&at[e][0];
        float4 A0=ap[0], A1=ap[1], A2=ap[2], A3=ap[3];
        float av[16] = {A0.x,A0.y,A0.z,A0.w,A1.x,A1.y,A1.z,A1.w,
                        A2.x,A2.y,A2.z,A2.w,A3.x,A3.y,A3.z,A3.w};
        #pragma unroll
        for(int n=0;n<16;n++){ acc0[n] += av[n]*w0; acc1[n] += av[n]*w1; }
    }
    float bb0 = bih[g0] + bhh[g0];
    float bb1 = bih[g1] + bhh[g1];
    #pragma unroll
    for(int n=0;n<16;n++){
        xg[(size_t)(row0+n)*G4_ + g0] = acc0[n] + bb0;
        xg[(size_t)(row0+n)*G4_ + g1] = acc1[n] + bb1;
    }
}

// ---------------------------------------------------------------- LSTM via MFMA, register-resident W_hh
// Block = 16 batch rows, 4 waves. Wave w owns j in [32w, 32w+32) for ALL 4 gates,
// so i/f/g/o of one (row,j) sit in the same lane (C-layout) -> per-lane cell update.
__global__ __launch_bounds__(256,1) void k_lstm_mfma(const float* __restrict__ xg, const float* __restrict__ Whh,
                                                     const float* __restrict__ vmask, float* __restrict__ hout){
    __shared__ u16 hbuf[16*HSTRIDE];     // h_{l-1} as bf16, [row][j] stride 136
    __shared__ float vmsh[16*64];
    int t = threadIdx.x;
    int wave = t >> 6, lane = t & 63;
    int quad = lane >> 4, lc = lane & 15;
    int b0 = blockIdx.x * 16;

    for(int i=t;i<16*HSTRIDE;i+=256) hbuf[i] = 0;
    for(int i=t;i<1024;i+=256) vmsh[i] = vmask[b0*64 + i];

    // B-fragments: bf[gate][ji][kt], B[k][n]=Whh[n][k], n = gate*128 + wave*32 + ji*16 + lc,
    // k = kt*32 + quad*8 + jj  (A/B frag: free index = lane&15, k = quad*8+jj)
    bf16x8 bf[4][2][4];
    #pragma unroll
    for(int gate=0;gate<4;gate++){
        #pragma unroll
        for(int ji=0;ji<2;ji++){
            int n = gate*128 + wave*32 + ji*16 + lc;
            const float* wr = Whh + (size_t)n*H_ + quad*8;
            #pragma unroll
            for(int kt=0;kt<4;kt++){
                const float4* p = (const float4*)(wr + kt*32);
                float4 w0 = p[0], w1 = p[1];
                bf16x8 f;
                f[0]=(short)f2bf(w0.x); f[1]=(short)f2bf(w0.y); f[2]=(short)f2bf(w0.z); f[3]=(short)f2bf(w0.w);
                f[4]=(short)f2bf(w1.x); f[5]=(short)f2bf(w1.y); f[6]=(short)f2bf(w1.z); f[7]=(short)f2bf(w1.w);
                bf[gate][ji][kt] = f;
            }
        }
    }

    float c8[2][4];
    #pragma unroll
    for(int ji=0;ji<2;ji++){
        #pragma unroll
        for(int r=0;r<4;r++) c8[ji][r]=0.f;
    }

    const float* pxg = xg + ((size_t)(b0 + quad*4))*64*G4_ + wave*32 + lc;
    float* ph = hout + ((size_t)(b0 + quad*4))*64*H_ + wave*32 + lc;

    __syncthreads();

    for(int l=0;l<64;l++){
        // A-frags: A[m=lc][k=kt*32+quad*8+jj] = h_{l-1}[row=lc][j=k]
        bf16x8 af[4];
        #pragma unroll
        for(int kt=0;kt<4;kt++)
            af[kt] = *(const bf16x8*)&hbuf[lc*HSTRIDE + kt*32 + quad*8];
        // xg prefetch (hidden under MFMA)
        float xgv[4][2][4];
        #pragma unroll
        for(int gate=0;gate<4;gate++){
            #pragma unroll
            for(int ji=0;ji<2;ji++){
                #pragma unroll
                for(int r=0;r<4;r++)
                    xgv[gate][ji][r] = pxg[(size_t)r*64*G4_ + (size_t)l*G4_ + gate*128 + ji*16];
            }
        }
        // MFMA: acc[a], a = gate*2+ji; D row = quad*4+reg = batch row, col = lc = n offset
        f32x4 acc[8];
        #pragma unroll
        for(int a=0;a<8;a++) acc[a] = (f32x4){0.f,0.f,0.f,0.f};
        #pragma unroll
        for(int kt=0;kt<4;kt++){
            #pragma unroll
            for(int a=0;a<8;a++)
                acc[a] = __builtin_amdgcn_mfma_f32_16x16x32_bf16(af[kt], bf[a>>1][a&1][kt], acc[a], 0,0,0);
        }
        __syncthreads();   // all waves done reading hbuf
        #pragma unroll
        for(int r=0;r<4;r++){
            float m = vmsh[(quad*4+r)*64 + l];
            #pragma unroll
            for(int ji=0;ji<2;ji++){
                float gi = acc[0+ji][r] + xgv[0][ji][r];
                float gf = acc[2+ji][r] + xgv[1][ji][r];
                float gg = acc[4+ji][r] + xgv[2][ji][r];
                float go = acc[6+ji][r] + xgv[3][ji][r];
                float c  = sigm(gf)*c8[ji][r] + sigm(gi)*tanhf(gg);
                float h  = sigm(go)*tanhf(c);
                c8[ji][r] = c;
                hbuf[(quad*4+r)*HSTRIDE + wave*32 + ji*16 + lc] = f2bf(h);
                ph[(size_t)r*64*H_ + (size_t)l*H_ + ji*16] = h * m;
            }
        }
        __syncthreads();   // h_l visible before next step's A-frag reads
    }
}

// ---------------------------------------------------------------- hp = (h_prev @ W_proj^T) * m
__global__ __launch_bounds__(256) void k_hp(const float* __restrict__ h, const float* __restrict__ Wproj,
                                            const float* __restrict__ vmask, float* __restrict__ hp){
    __shared__ float at[128][20];
    int row0 = blockIdx.x * 16;
    int t = threadIdx.x;
    #pragma unroll
    for(int i=0;i<8;i++){
        int idx = i*256 + t; int n = idx >> 7; int e = idx & 127;
        int r = row0 + n;
        at[e][n] = (r & 63) ? h[(size_t)(r-1)*H_ + e] : 0.f;
    }
    __syncthreads();
    int j = t & 127; int half = t >> 7;
    float acc[8];
    #pragma unroll
    for(int r=0;r<8;r++) acc[r]=0.f;
    for(int e=0;e<128;e++){
        float w = Wproj[j*H_ + e];
        const float4* ap = (const float4*)&at[e][half*8];
        float4 A0=ap[0], A1=ap[1];
        float av[8] = {A0.x,A0.y,A0.z,A0.w,A1.x,A1.y,A1.z,A1.w};
        #pragma unroll
        for(int r=0;r<8;r++) acc[r] += av[r]*w;
    }
    #pragma unroll
    for(int r=0;r<8;r++){
        int row = row0 + half*8 + r;
        hp[(size_t)row*E_ + j] = acc[r] * vmask[row];
    }
}

// ---------------------------------------------------------------- logits = h[b, len-1] . W_cls + b_cls
__global__ void k_logits(const float* __restrict__ h, const float* __restrict__ vmask,
                         const float* __restrict__ Wcls, const float* __restrict__ bcls, float* __restrict__ out){
    int b = blockIdx.x; int t = threadIdx.x; // 64 threads (1 wave)
    float s = vmask[b*64 + t];
    #pragma unroll
    for(int off=32;off;off>>=1) s += __shfl_down(s, off);
    s = __shfl(s, 0);
    int len = (int)(s + 0.5f); if(len < 1) len = 1;
    const float* hr = h + (size_t)(b*64 + len - 1)*H_;
    float val = hr[t]*Wcls[t] + hr[t+64]*Wcls[t+64];
    #pragma unroll
    for(int off=32;off;off>>=1) val += __shfl_down(val, off);
    if(t==0) out[b] = val + bcls[0];
}

// ---------------------------------------------------------------- diffusion loss (single fuse_eps on z_t)
__global__ __launch_bounds__(256) void k_diff_loss(const float* __restrict__ v, const float* __restrict__ hp,
        const float* __restrict__ eps, const int* __restrict__ tdiff, const float* __restrict__ vmask,
        const float* __restrict__ temb, const float* __restrict__ Wf, const float* __restrict__ bfu,
        const float* __restrict__ We1, const float* __restrict__ be1,
        const float* __restrict__ We2, const float* __restrict__ be2, float* __restrict__ lossacc){
    __shared__ float zs[16][128], hps[16][128];
    __shared__ float xt[256][20], y1t[128][20];
    __shared__ float ssh[16][2], ash[16][2];
    __shared__ float mrow[16]; __shared__ int trow[16];
    __shared__ float sabar[10];
    __shared__ float rb[4];
    int row0 = blockIdx.x * 16; int t = threadIdx.x;
    if(t==0){
        float p = 1.f;
        for(int k=0;k<10;k++){ float b = 1e-4f + (0.02f - 1e-4f)*k/9.f; p *= (1.f - b); sabar[k] = p; }
    }
    if(t < 16){
        int row = row0 + t; float m = vmask[row];
        mrow[t] = m; trow[t] = (m > 0.f) ? tdiff[row >> 6] : 1;
    }
    __syncthreads();
    #pragma unroll
    for(int i=0;i<8;i++){
        int idx = i*256 + t; int r = idx >> 7; int e = idx & 127; int row = row0 + r;
        float ab = sabar[trow[r]-1];
        float zt = (sqrtf(ab)*v[(size_t)row*E_ + e] + sqrtf(1.f - ab)*eps[(size_t)row*E_ + e]) * mrow[r];
        zs[r][e] = zt;
        hps[r][e] = hp[(size_t)row*E_ + e];
    }
    __syncthreads();
    if(t < 32){
        int r = t >> 1, k = t & 1;
        float s = bfu[k];
        for(int e=0;e<128;e++) s += zs[r][e]*Wf[k*256 + e];
        for(int e=0;e<128;e++) s += hps[r][e]*Wf[k*256 + 128 + e];
        ssh[r][k] = s;
    }
    __syncthreads();
    if(t < 16){
        float s0 = ssh[t][0], s1 = ssh[t][1];
        float mx = fmaxf(s0,s1);
        float e0 = __expf(s0-mx), e1 = __expf(s1-mx);
        float inv = 1.f/(e0+e1);
        ash[t][0] = e0*inv; ash[t][1] = e1*inv;
    }
    __syncthreads();
    {
        int e = t;
        if(e < 128){
            #pragma unroll
            for(int r=0;r<16;r++) xt[e][r] = ash[r][0]*zs[r][e] + ash[r][1]*hps[r][e];
        } else {
            int e2 = e - 128;
            #pragma unroll
            for(int r=0;r<16;r++) xt[e][r] = temb[trow[r]*E_ + e2];
        }
    }
    __syncthreads();
    int j = t & 127, half = t >> 7;
    {
        float acc[8]; float bb = be1[j];
        #pragma unroll
        for(int r=0;r<8;r++) acc[r] = bb;
        for(int e=0;e<256;e++){
            float w = We1[j*256 + e];
            const float4* xp = (const float4*)&xt[e][half*8];
            float4 X0=xp[0], X1=xp[1];
            float xv[8] = {X0.x,X0.y,X0.z,X0.w,X1.x,X1.y,X1.z,X1.w};
            #pragma unroll
            for(int r=0;r<8;r++) acc[r] += xv[r]*w;
        }
        #pragma unroll
        for(int r=0;r<8;r++) y1t[j][half*8 + r] = fmaxf(acc[r], 0.f);
    }
    __syncthreads();
    float acc2[8];
    {
        float bb = be2[j];
        #pragma unroll
        for(int r=0;r<8;r++) acc2[r] = bb;
        for(int e=0;e<128;e++){
            float w = We2[j*128 + e];
            const float4* yp = (const float4*)&y1t[e][half*8];
            float4 Y0=yp[0], Y1=yp[1];
            float yv[8] = {Y0.x,Y0.y,Y0.z,Y0.w,Y1.x,Y1.y,Y1.z,Y1.w};
            #pragma unroll
            for(int r=0;r<8;r++) acc2[r] += yv[r]*w;
        }
    }
    float lp = 0.f;
    #pragma unroll
    for(int r=0;r<8;r++){
        int rr = half*8 + r; int row = row0 + rr;
        float d = acc2[r] - eps[(size_t)row*E_ + j];
        lp += d*d*mrow[rr];
    }
    #pragma unroll
    for(int off=32;off;off>>=1) lp += __shfl_down(lp, off);
    if((t & 63) == 0) rb[t >> 6] = lp;
    __syncthreads();
    if(t == 0) atomicAdd(lossacc, rb[0]+rb[1]+rb[2]+rb[3]);
}

// ---------------------------------------------------------------- reverse diffusion: 10 fuse_eps steps in-kernel
__global__ __launch_bounds__(256) void k_reverse(const float* __restrict__ hp, const float* __restrict__ z0,
        const float* __restrict__ noise, const float* __restrict__ vmask, const float* __restrict__ temb,
        const float* __restrict__ Wf, const float* __restrict__ bfu,
        const float* __restrict__ We1, const float* __restrict__ be1,
        const float* __restrict__ We2, const float* __restrict__ be2, float* __restrict__ vsyn){
    __shared__ float zs[16][128], hps[16][128];
    __shared__ float xt[256][20], y1t[128][20];
    __shared__ float ssh[16][2], ash[16][2];
    __shared__ float mrow[16];
    __shared__ float sbeta[10], sabar[10];
    int row0 = blockIdx.x * 16; int t = threadIdx.x;
    if(t==0){
        float p = 1.f;
        for(int k=0;k<10;k++){ float b = 1e-4f + (0.02f - 1e-4f)*k/9.f; sbeta[k] = b; p *= (1.f - b); sabar[k] = p; }
    }
    if(t < 16) mrow[t] = vmask[row0 + t];
    __syncthreads();
    #pragma unroll
    for(int i=0;i<8;i++){
        int idx = i*256 + t; int r = idx >> 7; int e = idx & 127; int row = row0 + r;
        zs[r][e] = z0[(size_t)row*E_ + e];
        hps[r][e] = hp[(size_t)row*E_ + e];
    }
    __syncthreads();
    int j = t & 127, half = t >> 7;
    for(int s=0;s<10;s++){
        int kk = 10 - s;
        if(t < 32){
            int r = t >> 1, k = t & 1;
            float sv = bfu[k];
            for(int e=0;e<128;e++) sv += zs[r][e]*Wf[k*256 + e];
            for(int e=0;e<128;e++) sv += hps[r][e]*Wf[k*256 + 128 + e];
            ssh[r][k] = sv;
        }
        __syncthreads();
        if(t < 16){
            float s0 = ssh[t][0], s1 = ssh[t][1];
            float mx = fmaxf(s0,s1);
            float e0 = __expf(s0-mx), e1 = __expf(s1-mx);
            float inv = 1.f/(e0+e1);
            ash[t][0] = e0*inv; ash[t][1] = e1*inv;
        }
        __syncthreads();
        {
            int e = t;
            if(e < 128){
                #pragma unroll
                for(int r=0;r<16;r++) xt[e][r] = ash[r][0]*zs[r][e] + ash[r][1]*hps[r][e];
            } else {
                int e2 = e - 128;
                #pragma unroll
                for(int r=0;r<16;r++){
                    int tt = (mrow[r] > 0.f) ? kk : 1;
                    xt[e][r] = temb[tt*E_ + e2];
                }
            }
        }
        __syncthreads();
        float acc[8]; float bb = be1[j];
        #pragma unroll
        for(int r=0;r<8;r++) acc[r] = bb;
        for(int e=0;e<256;e++){
            float w = We1[j*256 + e];
            const float4* xp = (const float4*)&xt[e][half*8];
            float4 X0=xp[0], X1=xp[1];
            float xv[8] = {X0.x,X0.y,X0.z,X0.w,X1.x,X1.y,X1.z,X1.w};
            #pragma unroll
            for(int r=0;r<8;r++) acc[r] += xv[r]*w;
        }
        #pragma unroll
        for(int r=0;r<8;r++) y1t[j][half*8 + r] = fmaxf(acc[r], 0.f);
        __syncthreads();
        float acc2[8]; float bb2 = be2[j];
        #pragma unroll
        for(int r=0;r<8;r++) acc2[r] = bb2;
        for(int e=0;e<128;e++){
            float w = We2[j*128 + e];
            const float4* yp = (const float4*)&y1t[e][half*8];
            float4 Y0=yp[0], Y1=yp[1];
            float yv[8] = {Y0.x,Y0.y,Y0.z,Y0.w,Y1.x,Y1.y,Y1.z,Y1.w};
            #pragma unroll
            for(int r=0;r<8;r++) acc2[r] += yv[r]*w;
        }
        float beta = sbeta[kk-1];
        float c1 = beta / sqrtf(1.f - sabar[kk-1]);
        float c2 = 1.f / sqrtf(1.f - beta);
        float sb = sqrtf(beta);
        #pragma unroll
        for(int r=0;r<8;r++){
            int rr = half*8 + r; int row = row0 + rr;
            float z = zs[rr][j];
            float mean = (z - c1*acc2[r]) * c2;
            float nz = noise[((size_t)s*NROW + row)*E_ + j];
            float znew = (kk > 1) ? (mean + sb*nz) : mean;
            zs[rr][j] = znew * mrow[rr];
        }
        __syncthreads();
    }
    #pragma unroll
    for(int i=0;i<8;i++){
        int idx = i*256 + t; int r = idx >> 7; int e = idx & 127;
        vsyn[(size_t)(row0+r)*E_ + e] = zs[r][e];
    }
}

// ---------------------------------------------------------------- loss finalize
__global__ void k_finalize(const float* __restrict__ lossacc, const float* __restrict__ vmask, float* __restrict__ out){
    __shared__ float rb[4];
    int t = threadIdx.x;
    float s = 0.f;
    for(int i=t;i<NROW;i+=256) s += vmask[i];
    #pragma unroll
    for(int off=32;off;off>>=1) s += __shfl_down(s, off);
    if((t & 63) == 0) rb[t >> 6] = s;
    __syncthreads();
    if(t == 0){
        float denom = rb[0]+rb[1]+rb[2]+rb[3];
        if(denom < 1.f) denom = 1.f;
        out[256] = lossacc[0] / denom;
    }
}

extern "C" void kernel_launch(void* const* d_in, const int* in_sizes, int n_in,
                              void* d_out, int out_size, void* d_ws, size_t ws_size,
                              hipStream_t stream){
    const float* px    = (const float*)d_in[0];
    const float* vmask = (const float*)d_in[1];
    const int*   bins  = (const int*)d_in[2];
    const int*   tdiff = (const int*)d_in[3];
    const float* eps   = (const float*)d_in[4];
    const float* z0    = (const float*)d_in[5];
    const float* noise = (const float*)d_in[6];
    const float* Wv    = (const float*)d_in[7];
    const float* bemb  = (const float*)d_in[8];
    const float* Wih   = (const float*)d_in[9];
    const float* Whh   = (const float*)d_in[10];
    const float* bih   = (const float*)d_in[11];
    const float* bhh   = (const float*)d_in[12];
    const float* Wcls  = (const float*)d_in[13];
    const float* bcls  = (const float*)d_in[14];
    const float* Wproj = (const float*)d_in[15];
    const float* temb  = (const float*)d_in[16];
    const float* Wf    = (const float*)d_in[17];
    const float* bfu   = (const float*)d_in[18];
    const float* We1   = (const float*)d_in[19];
    const float* be1   = (const float*)d_in[20];
    const float* We2   = (const float*)d_in[21];
    const float* be2   = (const float*)d_in[22];
    float* out = (float*)d_out;

    float* ws      = (float*)d_ws;
    float* WT      = ws;                 // 8192*128
    float* v       = ws + 1048576;
    float* xg      = ws + 2097152;       // 8192*512
    float* h       = ws + 6291456;
    float* hp      = ws + 7340032;
    float* vsyn    = ws + 8388608;
    float* lossacc = ws + 9437184;

    hipLaunchKernelGGL(k_transpose_wv, dim3(V_/16), dim3(256), 0, stream, Wv, WT);
    hipLaunchKernelGGL(k_visit_embed, dim3(NROW), dim3(256), 0, stream, px, vmask, bins, bemb, WT, v);
    hipLaunchKernelGGL(k_gemm_xg, dim3(NROW/16), dim3(256), 0, stream, v, Wih, bih, bhh, xg);
    hipLaunchKernelGGL(k_lstm_mfma, dim3(B_/16), dim3(256), 0, stream, xg, Whh, vmask, h);
    hipLaunchKernelGGL(k_logits, dim3(B_), dim3(64), 0, stream, h, vmask, Wcls, bcls, out);
    hipLaunchKernelGGL(k_hp, dim3(NROW/16), dim3(256), 0, stream, h, Wproj, vmask, hp);
    hipMemsetAsync(lossacc, 0, sizeof(float), stream);
    hipLaunchKernelGGL(k_diff_loss, dim3(NROW/16), dim3(256), 0, stream,
                       v, hp, eps, tdiff, vmask, temb, Wf, bfu, We1, be1, We2, be2, lossacc);
    hipLaunchKernelGGL(k_reverse, dim3(NROW/16), dim3(256), 0, stream,
                       hp, z0, noise, vmask, temb, Wf, bfu, We1, be1, We2, be2, vsyn);
    hipLaunchKernelGGL(k_gemm_xg, dim3(NROW/16), dim3(256), 0, stream, vsyn, Wih, bih, bhh, xg);
    hipLaunchKernelGGL(k_lstm_mfma, dim3(B_/16), dim3(256), 0, stream, xg, Whh, vmask, h);
    hipLaunchKernelGGL(k_logits, dim3(B_), dim3(64), 0, stream, h, vmask, Wcls, bcls, out + 128);
    hipLaunchKernelGGL(k_finalize, dim3(1), dim3(256), 0, stream, lossacc, vmask, out);
}

// Round 4
// 995.930 us; speedup vs baseline: 1.8854x; 1.1895x over previous
//
#include <hip/hip_runtime.h>

#define B_ 128
#define L_ 64
#define V_ 8192
#define E_ 128
#define H_ 128
#define G4_ 512
#define NROW (B_*L_)
#define HSTRIDE 136
#define XS 264   // xbuf stride (bf16): 528B, 16B-aligned rows, 2-way banks (free)
#define YS 136   // y1buf stride (bf16): 272B
#define ZS 132   // zbuf/hpbuf stride (fp32)

typedef unsigned short u16;
typedef __attribute__((ext_vector_type(8))) short bf16x8;
typedef __attribute__((ext_vector_type(4))) float f32x4;

__device__ __forceinline__ float sigm(float x){ return 1.f/(1.f + __expf(-x)); }
__device__ __forceinline__ u16 f2bf(float f){
    union { unsigned int i; float f; } x; x.f = f;
    unsigned int r = x.i + 0x7fff + ((x.i >> 16) & 1);
    return (u16)(r >> 16);
}

// ---------------------------------------------------------------- transpose W_visit [E,V] -> WT [V,E]
__global__ __launch_bounds__(256) void k_transpose_wv(const float* __restrict__ Wv, float* __restrict__ WT){
    __shared__ float tile[16][129];
    int v0 = blockIdx.x * 16;
    int t = threadIdx.x;
    #pragma unroll
    for(int i=0;i<8;i++){
        int idx = i*256 + t; int e = idx >> 4; int vv = idx & 15;
        tile[vv][e] = Wv[(size_t)e*V_ + v0 + vv];
    }
    __syncthreads();
    #pragma unroll
    for(int i=0;i<8;i++){
        int idx = i*256 + t; int vv = idx >> 7; int e = idx & 127;
        WT[(size_t)(v0+vv)*E_ + e] = tile[vv][e];
    }
}

// ---------------------------------------------------------------- v = (x @ Wv^T + bin_embed[delta]) * m
__global__ __launch_bounds__(256) void k_visit_embed(const float* __restrict__ px, const float* __restrict__ vmask,
                                                     const int* __restrict__ bins, const float* __restrict__ bemb,
                                                     const float* __restrict__ WT, float* __restrict__ v){
    __shared__ int idxs[512];
    __shared__ int cnt;
    __shared__ int dsh;
    __shared__ float msh;
    int row = blockIdx.x; int l = row & 63;
    int t = threadIdx.x;
    if(t==0){
        cnt = 0;
        float m = vmask[row];
        int d = 0;
        if(l > 0){ d = bins[row] - bins[row-1]; d = d < 0 ? 0 : (d > 513 ? 513 : d); }
        if(!(m > 0.f)) d = 0;
        dsh = d; msh = m;
    }
    __syncthreads();
    const uint4* xr4 = (const uint4*)(px + (size_t)row * V_);
    for(int i=t;i<2048;i+=256){
        uint4 u = xr4[i];
        unsigned int w[4] = {u.x,u.y,u.z,u.w};
        #pragma unroll
        for(int j=0;j<4;j++){
            if(w[j]){ int p = atomicAdd(&cnt,1); if(p<512) idxs[p] = i*4 + j; }
        }
    }
    __syncthreads();
    int n = cnt; if(n > 512) n = 512;
    float m = msh;
    if(t < 128){
        float acc = bemb[dsh*E_ + t];
        for(int j=0;j<n;j++) acc += WT[(size_t)idxs[j]*E_ + t];
        v[(size_t)row*E_ + t] = acc * m;
    }
}

// ---------------------------------------------------------------- xg = A @ W_ih^T + b_ih + b_hh
__global__ __launch_bounds__(256) void k_gemm_xg(const float* __restrict__ A, const float* __restrict__ Wih,
                                                 const float* __restrict__ bih, const float* __restrict__ bhh,
                                                 float* __restrict__ xg){
    __shared__ float at[128][20];
    int row0 = blockIdx.x * 16;
    int t = threadIdx.x;
    #pragma unroll
    for(int i=0;i<8;i++){
        int idx = i*256 + t; int n = idx >> 7; int e = idx & 127;
        at[e][n] = A[(size_t)(row0+n)*E_ + e];
    }
    __syncthreads();
    int g0 = t, g1 = t + 256;
    float acc0[16], acc1[16];
    #pragma unroll
    for(int n=0;n<16;n++){ acc0[n]=0.f; acc1[n]=0.f; }
    for(int e=0;e<128;e++){
        float w0 = Wih[g0*E_ + e];
        float w1 = Wih[g1*E_ + e];
        const float4* ap = (const float4*)&at[e][0];
        float4 A0=ap[0], A1=ap[1], A2=ap[2], A3=ap[3];
        float av[16] = {A0.x,A0.y,A0.z,A0.w,A1.x,A1.y,A1.z,A1.w,
                        A2.x,A2.y,A2.z,A2.w,A3.x,A3.y,A3.z,A3.w};
        #pragma unroll
        for(int n=0;n<16;n++){ acc0[n] += av[n]*w0; acc1[n] += av[n]*w1; }
    }
    float bb0 = bih[g0] + bhh[g0];
    float bb1 = bih[g1] + bhh[g1];
    #pragma unroll
    for(int n=0;n<16;n++){
        xg[(size_t)(row0+n)*G4_ + g0] = acc0[n] + bb0;
        xg[(size_t)(row0+n)*G4_ + g1] = acc1[n] + bb1;
    }
}

// ---------------------------------------------------------------- LSTM via MFMA, register-resident W_hh
__global__ __launch_bounds__(256,1) void k_lstm_mfma(const float* __restrict__ xg, const float* __restrict__ Whh,
                                                     const float* __restrict__ vmask, float* __restrict__ hout){
    __shared__ u16 hbuf[16*HSTRIDE];
    __shared__ float vmsh[16*64];
    int t = threadIdx.x;
    int wave = t >> 6, lane = t & 63;
    int quad = lane >> 4, lc = lane & 15;
    int b0 = blockIdx.x * 16;

    for(int i=t;i<16*HSTRIDE;i+=256) hbuf[i] = 0;
    for(int i=t;i<1024;i+=256) vmsh[i] = vmask[b0*64 + i];

    bf16x8 bf[4][2][4];
    #pragma unroll
    for(int gate=0;gate<4;gate++){
        #pragma unroll
        for(int ji=0;ji<2;ji++){
            int n = gate*128 + wave*32 + ji*16 + lc;
            const float* wr = Whh + (size_t)n*H_ + quad*8;
            #pragma unroll
            for(int kt=0;kt<4;kt++){
                const float4* p = (const float4*)(wr + kt*32);
                float4 w0 = p[0], w1 = p[1];
                bf16x8 f;
                f[0]=(short)f2bf(w0.x); f[1]=(short)f2bf(w0.y); f[2]=(short)f2bf(w0.z); f[3]=(short)f2bf(w0.w);
                f[4]=(short)f2bf(w1.x); f[5]=(short)f2bf(w1.y); f[6]=(short)f2bf(w1.z); f[7]=(short)f2bf(w1.w);
                bf[gate][ji][kt] = f;
            }
        }
    }

    float c8[2][4];
    #pragma unroll
    for(int ji=0;ji<2;ji++){
        #pragma unroll
        for(int r=0;r<4;r++) c8[ji][r]=0.f;
    }

    const float* pxg = xg + ((size_t)(b0 + quad*4))*64*G4_ + wave*32 + lc;
    float* ph = hout + ((size_t)(b0 + quad*4))*64*H_ + wave*32 + lc;

    __syncthreads();

    for(int l=0;l<64;l++){
        bf16x8 af[4];
        #pragma unroll
        for(int kt=0;kt<4;kt++)
            af[kt] = *(const bf16x8*)&hbuf[lc*HSTRIDE + kt*32 + quad*8];
        float xgv[4][2][4];
        #pragma unroll
        for(int gate=0;gate<4;gate++){
            #pragma unroll
            for(int ji=0;ji<2;ji++){
                #pragma unroll
                for(int r=0;r<4;r++)
                    xgv[gate][ji][r] = pxg[(size_t)r*64*G4_ + (size_t)l*G4_ + gate*128 + ji*16];
            }
        }
        f32x4 acc[8];
        #pragma unroll
        for(int a=0;a<8;a++) acc[a] = (f32x4){0.f,0.f,0.f,0.f};
        #pragma unroll
        for(int kt=0;kt<4;kt++){
            #pragma unroll
            for(int a=0;a<8;a++)
                acc[a] = __builtin_amdgcn_mfma_f32_16x16x32_bf16(af[kt], bf[a>>1][a&1][kt], acc[a], 0,0,0);
        }
        __syncthreads();
        #pragma unroll
        for(int r=0;r<4;r++){
            float m = vmsh[(quad*4+r)*64 + l];
            #pragma unroll
            for(int ji=0;ji<2;ji++){
                float gi = acc[0+ji][r] + xgv[0][ji][r];
                float gf = acc[2+ji][r] + xgv[1][ji][r];
                float gg = acc[4+ji][r] + xgv[2][ji][r];
                float go = acc[6+ji][r] + xgv[3][ji][r];
                float c  = sigm(gf)*c8[ji][r] + sigm(gi)*tanhf(gg);
                float h  = sigm(go)*tanhf(c);
                c8[ji][r] = c;
                hbuf[(quad*4+r)*HSTRIDE + wave*32 + ji*16 + lc] = f2bf(h);
                ph[(size_t)r*64*H_ + (size_t)l*H_ + ji*16] = h * m;
            }
        }
        __syncthreads();
    }
}

// ---------------------------------------------------------------- hp = (h_prev @ W_proj^T) * m
__global__ __launch_bounds__(256) void k_hp(const float* __restrict__ h, const float* __restrict__ Wproj,
                                            const float* __restrict__ vmask, float* __restrict__ hp){
    __shared__ float at[128][20];
    int row0 = blockIdx.x * 16;
    int t = threadIdx.x;
    #pragma unroll
    for(int i=0;i<8;i++){
        int idx = i*256 + t; int n = idx >> 7; int e = idx & 127;
        int r = row0 + n;
        at[e][n] = (r & 63) ? h[(size_t)(r-1)*H_ + e] : 0.f;
    }
    __syncthreads();
    int j = t & 127; int half = t >> 7;
    float acc[8];
    #pragma unroll
    for(int r=0;r<8;r++) acc[r]=0.f;
    for(int e=0;e<128;e++){
        float w = Wproj[j*H_ + e];
        const float4* ap = (const float4*)&at[e][half*8];
        float4 A0=ap[0], A1=ap[1];
        float av[8] = {A0.x,A0.y,A0.z,A0.w,A1.x,A1.y,A1.z,A1.w};
        #pragma unroll
        for(int r=0;r<8;r++) acc[r] += av[r]*w;
    }
    #pragma unroll
    for(int r=0;r<8;r++){
        int row = row0 + half*8 + r;
        hp[(size_t)row*E_ + j] = acc[r] * vmask[row];
    }
}

// ---------------------------------------------------------------- logits
__global__ void k_logits(const float* __restrict__ h, const float* __restrict__ vmask,
                         const float* __restrict__ Wcls, const float* __restrict__ bcls, float* __restrict__ out){
    int b = blockIdx.x; int t = threadIdx.x;
    float s = vmask[b*64 + t];
    #pragma unroll
    for(int off=32;off;off>>=1) s += __shfl_down(s, off);
    s = __shfl(s, 0);
    int len = (int)(s + 0.5f); if(len < 1) len = 1;
    const float* hr = h + (size_t)(b*64 + len - 1)*H_;
    float val = hr[t]*Wcls[t] + hr[t+64]*Wcls[t+64];
    #pragma unroll
    for(int off=32;off;off>>=1) val += __shfl_down(val, off);
    if(t==0) out[b] = val + bcls[0];
}

// ---------------------------------------------------------------- diffusion loss via MFMA (single fuse_eps)
__global__ __launch_bounds__(256,1) void k_diff_loss_mfma(const float* __restrict__ v, const float* __restrict__ hp,
        const float* __restrict__ eps, const int* __restrict__ tdiff, const float* __restrict__ vmask,
        const float* __restrict__ temb, const float* __restrict__ Wf, const float* __restrict__ bfu,
        const float* __restrict__ We1, const float* __restrict__ be1,
        const float* __restrict__ We2, const float* __restrict__ be2, float* __restrict__ lossacc){
    __shared__ float zbuf[16*ZS], hpbuf[16*ZS];
    __shared__ __align__(16) u16 xbuf[16*XS];
    __shared__ __align__(16) u16 y1buf[16*YS];
    __shared__ float wfsh[512];
    __shared__ float ssh[16][2], hpd[16][2];
    __shared__ float mrow[16]; __shared__ int trow[16];
    __shared__ float sabar[10];
    int row0 = blockIdx.x * 16; int t = threadIdx.x;
    int wave = t >> 6, lane = t & 63, quad = lane >> 4, lc = lane & 15;

    if(t==0){
        float p = 1.f;
        for(int k=0;k<10;k++){ float b = 1e-4f + (0.02f - 1e-4f)*k/9.f; p *= (1.f - b); sabar[k] = p; }
    }
    if(t < 16){
        int row = row0 + t; float m = vmask[row];
        mrow[t] = m; trow[t] = (m > 0.f) ? tdiff[row >> 6] : 1;
    }
    for(int i=t;i<512;i+=256) wfsh[i] = Wf[i];
    __syncthreads();
    // z_t and hp into LDS (fp32)
    #pragma unroll
    for(int i=0;i<8;i++){
        int flat = i*256 + t; int r = flat >> 7; int e = flat & 127; int row = row0 + r;
        float ab = sabar[trow[r]-1];
        zbuf[r*ZS + e] = (sqrtf(ab)*v[(size_t)row*E_ + e] + sqrtf(1.f - ab)*eps[(size_t)row*E_ + e]) * mrow[r];
        hpbuf[r*ZS + e] = hp[(size_t)row*E_ + e];
    }
    // weight fragments (wave-owned 32 output cols)
    bf16x8 wf1[2][8], wf2[2][4];
    float be1v[2], be2v[2];
    #pragma unroll
    for(int nt=0;nt<2;nt++){
        int n = wave*32 + nt*16 + lc;
        be1v[nt] = be1[n]; be2v[nt] = be2[n];
        const float* w1 = We1 + (size_t)n*256 + quad*8;
        #pragma unroll
        for(int kt=0;kt<8;kt++){
            const float4* p = (const float4*)(w1 + kt*32);
            float4 a = p[0], b = p[1];
            bf16x8 f;
            f[0]=(short)f2bf(a.x); f[1]=(short)f2bf(a.y); f[2]=(short)f2bf(a.z); f[3]=(short)f2bf(a.w);
            f[4]=(short)f2bf(b.x); f[5]=(short)f2bf(b.y); f[6]=(short)f2bf(b.z); f[7]=(short)f2bf(b.w);
            wf1[nt][kt] = f;
        }
        const float* w2 = We2 + (size_t)n*128 + quad*8;
        #pragma unroll
        for(int kt=0;kt<4;kt++){
            const float4* p = (const float4*)(w2 + kt*32);
            float4 a = p[0], b = p[1];
            bf16x8 f;
            f[0]=(short)f2bf(a.x); f[1]=(short)f2bf(a.y); f[2]=(short)f2bf(a.z); f[3]=(short)f2bf(a.w);
            f[4]=(short)f2bf(b.x); f[5]=(short)f2bf(b.y); f[6]=(short)f2bf(b.z); f[7]=(short)f2bf(b.w);
            wf2[nt][kt] = f;
        }
    }
    __syncthreads();
    // hp·Wf[:,128:256] + bfu (precompute)  |  z·Wf[:,0:128]  — 16 rows × 2 k × 8 lanes
    {
        int row = t >> 4, k = (t >> 3) & 1, sub = t & 7;
        float p = 0.f, q = 0.f;
        #pragma unroll
        for(int i=0;i<16;i++){
            p += hpbuf[row*ZS + sub*16 + i] * wfsh[k*256 + 128 + sub*16 + i];
            q += zbuf[row*ZS + sub*16 + i]  * wfsh[k*256 + sub*16 + i];
        }
        p += __shfl_down(p,4); p += __shfl_down(p,2); p += __shfl_down(p,1);
        q += __shfl_down(q,4); q += __shfl_down(q,2); q += __shfl_down(q,1);
        if(sub == 0){ hpd[row][k] = p + bfu[k]; ssh[row][k] = q; }
    }
    __syncthreads();
    // build x (bf16)
    {
        int row = t >> 4, c0 = (t & 15) * 16;
        float s0 = ssh[row][0] + hpd[row][0], s1 = ssh[row][1] + hpd[row][1];
        float a0 = 1.f/(1.f + __expf(s1 - s0)), a1 = 1.f - a0;
        int tt = trow[row];
        #pragma unroll
        for(int i=0;i<16;i++){
            int c = c0 + i;
            float val = (c < 128) ? (a0*zbuf[row*ZS + c] + a1*hpbuf[row*ZS + c])
                                  : temb[tt*E_ + (c - 128)];
            xbuf[row*XS + c] = f2bf(val);
        }
    }
    __syncthreads();
    // layer 1
    f32x4 acc1[2];
    acc1[0] = (f32x4){0.f,0.f,0.f,0.f}; acc1[1] = (f32x4){0.f,0.f,0.f,0.f};
    #pragma unroll
    for(int kt=0;kt<8;kt++){
        bf16x8 af = *(const bf16x8*)&xbuf[lc*XS + kt*32 + quad*8];
        acc1[0] = __builtin_amdgcn_mfma_f32_16x16x32_bf16(af, wf1[0][kt], acc1[0], 0,0,0);
        acc1[1] = __builtin_amdgcn_mfma_f32_16x16x32_bf16(af, wf1[1][kt], acc1[1], 0,0,0);
    }
    #pragma unroll
    for(int nt=0;nt<2;nt++){
        #pragma unroll
        for(int r=0;r<4;r++)
            y1buf[(quad*4+r)*YS + wave*32 + nt*16 + lc] = f2bf(fmaxf(acc1[nt][r] + be1v[nt], 0.f));
    }
    __syncthreads();
    // layer 2
    f32x4 acc2[2];
    acc2[0] = (f32x4){0.f,0.f,0.f,0.f}; acc2[1] = (f32x4){0.f,0.f,0.f,0.f};
    #pragma unroll
    for(int kt=0;kt<4;kt++){
        bf16x8 af = *(const bf16x8*)&y1buf[lc*YS + kt*32 + quad*8];
        acc2[0] = __builtin_amdgcn_mfma_f32_16x16x32_bf16(af, wf2[0][kt], acc2[0], 0,0,0);
        acc2[1] = __builtin_amdgcn_mfma_f32_16x16x32_bf16(af, wf2[1][kt], acc2[1], 0,0,0);
    }
    // loss
    float lp = 0.f;
    #pragma unroll
    for(int nt=0;nt<2;nt++){
        int n = wave*32 + nt*16 + lc;
        #pragma unroll
        for(int r=0;r<4;r++){
            int m = quad*4 + r;
            float d = (acc2[nt][r] + be2v[nt]) - eps[(size_t)(row0+m)*E_ + n];
            lp += d*d*mrow[m];
        }
    }
    #pragma unroll
    for(int off=32;off;off>>=1) lp += __shfl_down(lp, off);
    if(lane == 0) atomicAdd(lossacc, lp);
}

// ---------------------------------------------------------------- reverse diffusion via MFMA, 10 steps in-kernel
__global__ __launch_bounds__(256,1) void k_reverse_mfma(const float* __restrict__ hp, const float* __restrict__ z0,
        const float* __restrict__ noise, const float* __restrict__ vmask, const float* __restrict__ temb,
        const float* __restrict__ Wf, const float* __restrict__ bfu,
        const float* __restrict__ We1, const float* __restrict__ be1,
        const float* __restrict__ We2, const float* __restrict__ be2, float* __restrict__ vsyn){
    __shared__ float zbuf[16*ZS], hpbuf[16*ZS];
    __shared__ __align__(16) u16 xbuf[16*XS];
    __shared__ __align__(16) u16 y1buf[16*YS];
    __shared__ float wfsh[512];
    __shared__ float ssh[16][2], hpd[16][2];
    __shared__ float mrow[16];
    __shared__ float sbeta[10], sabar[10];
    int row0 = blockIdx.x * 16; int t = threadIdx.x;
    int wave = t >> 6, lane = t & 63, quad = lane >> 4, lc = lane & 15;

    if(t==0){
        float p = 1.f;
        for(int k=0;k<10;k++){ float b = 1e-4f + (0.02f - 1e-4f)*k/9.f; sbeta[k] = b; p *= (1.f - b); sabar[k] = p; }
    }
    if(t < 16) mrow[t] = vmask[row0 + t];
    for(int i=t;i<512;i+=256) wfsh[i] = Wf[i];
    #pragma unroll
    for(int i=0;i<8;i++){
        int flat = i*256 + t; int r = flat >> 7; int e = flat & 127; int row = row0 + r;
        zbuf[r*ZS + e]  = z0[(size_t)row*E_ + e];
        hpbuf[r*ZS + e] = hp[(size_t)row*E_ + e];
    }
    // weight fragments
    bf16x8 wf1[2][8], wf2[2][4];
    float be1v[2], be2v[2];
    #pragma unroll
    for(int nt=0;nt<2;nt++){
        int n = wave*32 + nt*16 + lc;
        be1v[nt] = be1[n]; be2v[nt] = be2[n];
        const float* w1 = We1 + (size_t)n*256 + quad*8;
        #pragma unroll
        for(int kt=0;kt<8;kt++){
            const float4* p = (const float4*)(w1 + kt*32);
            float4 a = p[0], b = p[1];
            bf16x8 f;
            f[0]=(short)f2bf(a.x); f[1]=(short)f2bf(a.y); f[2]=(short)f2bf(a.z); f[3]=(short)f2bf(a.w);
            f[4]=(short)f2bf(b.x); f[5]=(short)f2bf(b.y); f[6]=(short)f2bf(b.z); f[7]=(short)f2bf(b.w);
            wf1[nt][kt] = f;
        }
        const float* w2 = We2 + (size_t)n*128 + quad*8;
        #pragma unroll
        for(int kt=0;kt<4;kt++){
            const float4* p = (const float4*)(w2 + kt*32);
            float4 a = p[0], b = p[1];
            bf16x8 f;
            f[0]=(short)f2bf(a.x); f[1]=(short)f2bf(a.y); f[2]=(short)f2bf(a.z); f[3]=(short)f2bf(a.w);
            f[4]=(short)f2bf(b.x); f[5]=(short)f2bf(b.y); f[6]=(short)f2bf(b.z); f[7]=(short)f2bf(b.w);
            wf2[nt][kt] = f;
        }
    }
    __syncthreads();
    // hp·Wf[:,128:256] + bfu precompute
    {
        int row = t >> 4, k = (t >> 3) & 1, sub = t & 7;
        float p = 0.f;
        #pragma unroll
        for(int i=0;i<16;i++)
            p += hpbuf[row*ZS + sub*16 + i] * wfsh[k*256 + 128 + sub*16 + i];
        p += __shfl_down(p,4); p += __shfl_down(p,2); p += __shfl_down(p,1);
        if(sub == 0) hpd[row][k] = p + bfu[k];
    }
    __syncthreads();

    for(int s=0;s<10;s++){
        int kk = 10 - s;
        // gate: z·Wf[:,0:128]
        {
            int row = t >> 4, k = (t >> 3) & 1, sub = t & 7;
            float q = 0.f;
            #pragma unroll
            for(int i=0;i<16;i++)
                q += zbuf[row*ZS + sub*16 + i] * wfsh[k*256 + sub*16 + i];
            q += __shfl_down(q,4); q += __shfl_down(q,2); q += __shfl_down(q,1);
            if(sub == 0) ssh[row][k] = q + hpd[row][k];
        }
        __syncthreads();
        // build x
        {
            int row = t >> 4, c0 = (t & 15) * 16;
            float s0 = ssh[row][0], s1 = ssh[row][1];
            float a0 = 1.f/(1.f + __expf(s1 - s0)), a1 = 1.f - a0;
            int tt = (mrow[row] > 0.f) ? kk : 1;
            #pragma unroll
            for(int i=0;i<16;i++){
                int c = c0 + i;
                float val = (c < 128) ? (a0*zbuf[row*ZS + c] + a1*hpbuf[row*ZS + c])
                                      : temb[tt*E_ + (c - 128)];
                xbuf[row*XS + c] = f2bf(val);
            }
        }
        __syncthreads();
        // layer 1
        f32x4 acc1[2];
        acc1[0] = (f32x4){0.f,0.f,0.f,0.f}; acc1[1] = (f32x4){0.f,0.f,0.f,0.f};
        #pragma unroll
        for(int kt=0;kt<8;kt++){
            bf16x8 af = *(const bf16x8*)&xbuf[lc*XS + kt*32 + quad*8];
            acc1[0] = __builtin_amdgcn_mfma_f32_16x16x32_bf16(af, wf1[0][kt], acc1[0], 0,0,0);
            acc1[1] = __builtin_amdgcn_mfma_f32_16x16x32_bf16(af, wf1[1][kt], acc1[1], 0,0,0);
        }
        #pragma unroll
        for(int nt=0;nt<2;nt++){
            #pragma unroll
            for(int r=0;r<4;r++)
                y1buf[(quad*4+r)*YS + wave*32 + nt*16 + lc] = f2bf(fmaxf(acc1[nt][r] + be1v[nt], 0.f));
        }
        __syncthreads();
        // layer 2
        f32x4 acc2[2];
        acc2[0] = (f32x4){0.f,0.f,0.f,0.f}; acc2[1] = (f32x4){0.f,0.f,0.f,0.f};
        #pragma unroll
        for(int kt=0;kt<4;kt++){
            bf16x8 af = *(const bf16x8*)&y1buf[lc*YS + kt*32 + quad*8];
            acc2[0] = __builtin_amdgcn_mfma_f32_16x16x32_bf16(af, wf2[0][kt], acc2[0], 0,0,0);
            acc2[1] = __builtin_amdgcn_mfma_f32_16x16x32_bf16(af, wf2[1][kt], acc2[1], 0,0,0);
        }
        // z update (C-layout positions)
        float beta = sbeta[kk-1];
        float c1 = beta / sqrtf(1.f - sabar[kk-1]);
        float c2 = 1.f / sqrtf(1.f - beta);
        float sb = sqrtf(beta);
        #pragma unroll
        for(int nt=0;nt<2;nt++){
            int n = wave*32 + nt*16 + lc;
            #pragma unroll
            for(int r=0;r<4;r++){
                int m = quad*4 + r;
                float e = acc2[nt][r] + be2v[nt];
                float z = zbuf[m*ZS + n];
                float mean = (z - c1*e) * c2;
                float nz = noise[((size_t)s*NROW + row0 + m)*E_ + n];
                float znew = (kk > 1) ? (mean + sb*nz) : mean;
                zbuf[m*ZS + n] = znew * mrow[m];
            }
        }
        __syncthreads();
    }
    // store v_syn
    {
        int row = t >> 4, c0 = (t & 15) * 16;
        if(c0 < 128){
            #pragma unroll
            for(int i=0;i<16;i++)
                vsyn[(size_t)(row0+row)*E_ + c0 + i] = zbuf[row*ZS + c0 + i];
        }
    }
    // second half of columns (c0 in [128,256) unused: only 128 cols) -> handled above for c0<128;
    // threads with c0>=128 write the other 8 rows' halves:
    {
        int row = t >> 4, c0 = (t & 15) * 16;
        if(c0 >= 128){
            // remap: these 8 col-groups cover nothing; instead duplicate-safe no-op
        }
    }
}

// ---------------------------------------------------------------- loss finalize
__global__ void k_finalize(const float* __restrict__ lossacc, const float* __restrict__ vmask, float* __restrict__ out){
    __shared__ float rb[4];
    int t = threadIdx.x;
    float s = 0.f;
    for(int i=t;i<NROW;i+=256) s += vmask[i];
    #pragma unroll
    for(int off=32;off;off>>=1) s += __shfl_down(s, off);
    if((t & 63) == 0) rb[t >> 6] = s;
    __syncthreads();
    if(t == 0){
        float denom = rb[0]+rb[1]+rb[2]+rb[3];
        if(denom < 1.f) denom = 1.f;
        out[256] = lossacc[0] / denom;
    }
}

extern "C" void kernel_launch(void* const* d_in, const int* in_sizes, int n_in,
                              void* d_out, int out_size, void* d_ws, size_t ws_size,
                              hipStream_t stream){
    const float* px    = (const float*)d_in[0];
    const float* vmask = (const float*)d_in[1];
    const int*   bins  = (const int*)d_in[2];
    const int*   tdiff = (const int*)d_in[3];
    const float* eps   = (const float*)d_in[4];
    const float* z0    = (const float*)d_in[5];
    const float* noise = (const float*)d_in[6];
    const float* Wv    = (const float*)d_in[7];
    const float* bemb  = (const float*)d_in[8];
    const float* Wih   = (const float*)d_in[9];
    const float* Whh   = (const float*)d_in[10];
    const float* bih   = (const float*)d_in[11];
    const float* bhh   = (const float*)d_in[12];
    const float* Wcls  = (const float*)d_in[13];
    const float* bcls  = (const float*)d_in[14];
    const float* Wproj = (const float*)d_in[15];
    const float* temb  = (const float*)d_in[16];
    const float* Wf    = (const float*)d_in[17];
    const float* bfu   = (const float*)d_in[18];
    const float* We1   = (const float*)d_in[19];
    const float* be1   = (const float*)d_in[20];
    const float* We2   = (const float*)d_in[21];
    const float* be2   = (const float*)d_in[22];
    float* out = (float*)d_out;

    float* ws      = (float*)d_ws;
    float* WT      = ws;
    float* v       = ws + 1048576;
    float* xg      = ws + 2097152;
    float* h       = ws + 6291456;
    float* hp      = ws + 7340032;
    float* vsyn    = ws + 8388608;
    float* lossacc = ws + 9437184;

    hipLaunchKernelGGL(k_transpose_wv, dim3(V_/16), dim3(256), 0, stream, Wv, WT);
    hipLaunchKernelGGL(k_visit_embed, dim3(NROW), dim3(256), 0, stream, px, vmask, bins, bemb, WT, v);
    hipLaunchKernelGGL(k_gemm_xg, dim3(NROW/16), dim3(256), 0, stream, v, Wih, bih, bhh, xg);
    hipLaunchKernelGGL(k_lstm_mfma, dim3(B_/16), dim3(256), 0, stream, xg, Whh, vmask, h);
    hipLaunchKernelGGL(k_logits, dim3(B_), dim3(64), 0, stream, h, vmask, Wcls, bcls, out);
    hipLaunchKernelGGL(k_hp, dim3(NROW/16), dim3(256), 0, stream, h, Wproj, vmask, hp);
    hipMemsetAsync(lossacc, 0, sizeof(float), stream);
    hipLaunchKernelGGL(k_diff_loss_mfma, dim3(NROW/16), dim3(256), 0, stream,
                       v, hp, eps, tdiff, vmask, temb, Wf, bfu, We1, be1, We2, be2, lossacc);
    hipLaunchKernelGGL(k_reverse_mfma, dim3(NROW/16), dim3(256), 0, stream,
                       hp, z0, noise, vmask, temb, Wf, bfu, We1, be1, We2, be2, vsyn);
    hipLaunchKernelGGL(k_gemm_xg, dim3(NROW/16), dim3(256), 0, stream, vsyn, Wih, bih, bhh, xg);
    hipLaunchKernelGGL(k_lstm_mfma, dim3(B_/16), dim3(256), 0, stream, xg, Whh, vmask, h);
    hipLaunchKernelGGL(k_logits, dim3(B_), dim3(64), 0, stream, h, vmask, Wcls, bcls, out + 128);
    hipLaunchKernelGGL(k_finalize, dim3(1), dim3(256), 0, stream, lossacc, vmask, out);
}

// Round 5
// 901.729 us; speedup vs baseline: 2.0823x; 1.1045x over previous
//
#include <hip/hip_runtime.h>

#define B_ 128
#define L_ 64
#define V_ 8192
#define E_ 128
#define H_ 128
#define G4_ 512
#define NROW (B_*L_)
#define HSTRIDE 136
#define AS 136   // bf16 A-tile stride
#define XS 264
#define YS 136
#define ZS 132

typedef unsigned short u16;
typedef __attribute__((ext_vector_type(8))) short bf16x8;
typedef __attribute__((ext_vector_type(4))) float f32x4;

__device__ __forceinline__ float sigm(float x){ return 1.f/(1.f + __expf(-x)); }
__device__ __forceinline__ float ftanh(float x){ float e = __expf(2.f*x); return 1.f - 2.f/(e + 1.f); }
__device__ __forceinline__ u16 f2bf(float f){
    union { unsigned int i; float f; } x; x.f = f;
    unsigned int r = x.i + 0x7fff + ((x.i >> 16) & 1);
    return (u16)(r >> 16);
}
// raw barrier: LDS-only sync, no vmcnt drain (global stores/loads stay in flight)
#define LBAR() asm volatile("s_waitcnt lgkmcnt(0)\ns_barrier" ::: "memory")

__device__ __forceinline__ bf16x8 pack8(const float* p){
    const float4* q = (const float4*)p;
    float4 a = q[0], b = q[1];
    bf16x8 f;
    f[0]=(short)f2bf(a.x); f[1]=(short)f2bf(a.y); f[2]=(short)f2bf(a.z); f[3]=(short)f2bf(a.w);
    f[4]=(short)f2bf(b.x); f[5]=(short)f2bf(b.y); f[6]=(short)f2bf(b.z); f[7]=(short)f2bf(b.w);
    return f;
}

// ---------------------------------------------------------------- transpose W_visit [E,V] -> WT [V,E]
__global__ __launch_bounds__(256) void k_transpose_wv(const float* __restrict__ Wv, float* __restrict__ WT){
    __shared__ float tile[16][129];
    int v0 = blockIdx.x * 16;
    int t = threadIdx.x;
    #pragma unroll
    for(int i=0;i<8;i++){
        int idx = i*256 + t; int e = idx >> 4; int vv = idx & 15;
        tile[vv][e] = Wv[(size_t)e*V_ + v0 + vv];
    }
    __syncthreads();
    #pragma unroll
    for(int i=0;i<8;i++){
        int idx = i*256 + t; int vv = idx >> 7; int e = idx & 127;
        WT[(size_t)(v0+vv)*E_ + e] = tile[vv][e];
    }
}

// ---------------------------------------------------------------- v = (x @ Wv^T + bin_embed[delta]) * m
__global__ __launch_bounds__(256) void k_visit_embed(const float* __restrict__ px, const float* __restrict__ vmask,
                                                     const int* __restrict__ bins, const float* __restrict__ bemb,
                                                     const float* __restrict__ WT, float* __restrict__ v){
    __shared__ int idxs[512];
    __shared__ int cnt;
    __shared__ int dsh;
    __shared__ float msh;
    int row = blockIdx.x; int l = row & 63;
    int t = threadIdx.x;
    if(t==0){
        cnt = 0;
        float m = vmask[row];
        int d = 0;
        if(l > 0){ d = bins[row] - bins[row-1]; d = d < 0 ? 0 : (d > 513 ? 513 : d); }
        if(!(m > 0.f)) d = 0;
        dsh = d; msh = m;
    }
    __syncthreads();
    const uint4* xr4 = (const uint4*)(px + (size_t)row * V_);
    for(int i=t;i<2048;i+=256){
        uint4 u = xr4[i];
        unsigned int w[4] = {u.x,u.y,u.z,u.w};
        #pragma unroll
        for(int j=0;j<4;j++){
            if(w[j]){ int p = atomicAdd(&cnt,1); if(p<512) idxs[p] = i*4 + j; }
        }
    }
    __syncthreads();
    int n = cnt; if(n > 512) n = 512;
    float m = msh;
    if(t < 128){
        float acc = bemb[dsh*E_ + t];
        for(int j=0;j<n;j++) acc += WT[(size_t)idxs[j]*E_ + t];
        v[(size_t)row*E_ + t] = acc * m;
    }
}

// ---------------------------------------------------------------- xg = A @ W_ih^T + b_ih + b_hh (MFMA)
__global__ __launch_bounds__(256,2) void k_gemm_xg(const float* __restrict__ A, const float* __restrict__ Wih,
                                                   const float* __restrict__ bih, const float* __restrict__ bhh,
                                                   float* __restrict__ xg){
    __shared__ __align__(16) u16 abuf[16*AS];
    int t = threadIdx.x, wave = t >> 6, lane = t & 63, quad = lane >> 4, lc = lane & 15;
    int row0 = blockIdx.x * 16;
    #pragma unroll
    for(int i=0;i<8;i++){
        int flat = i*256 + t; int r = flat >> 7, e = flat & 127;
        abuf[r*AS + e] = f2bf(A[(size_t)(row0+r)*E_ + e]);
    }
    bf16x8 wfr[8][4]; float bb[8];
    #pragma unroll
    for(int nt=0;nt<8;nt++){
        int n = wave*128 + nt*16 + lc;
        bb[nt] = bih[n] + bhh[n];
        const float* wr = Wih + (size_t)n*E_ + quad*8;
        #pragma unroll
        for(int kt=0;kt<4;kt++) wfr[nt][kt] = pack8(wr + kt*32);
    }
    __syncthreads();
    f32x4 acc[8];
    #pragma unroll
    for(int nt=0;nt<8;nt++) acc[nt] = (f32x4){0.f,0.f,0.f,0.f};
    #pragma unroll
    for(int kt=0;kt<4;kt++){
        bf16x8 af = *(const bf16x8*)&abuf[lc*AS + kt*32 + quad*8];
        #pragma unroll
        for(int nt=0;nt<8;nt++)
            acc[nt] = __builtin_amdgcn_mfma_f32_16x16x32_bf16(af, wfr[nt][kt], acc[nt], 0,0,0);
    }
    #pragma unroll
    for(int nt=0;nt<8;nt++){
        int n = wave*128 + nt*16 + lc;
        #pragma unroll
        for(int r=0;r<4;r++)
            xg[(size_t)(row0 + quad*4 + r)*G4_ + n] = acc[nt][r] + bb[nt];
    }
}

// ---------------------------------------------------------------- LSTM via MFMA: raw barrier, dbuf h, xg prefetch
__device__ __forceinline__ void lstm_step(int l, const float* pxg, float* ph,
        const u16* bufr, u16* bufw, const bf16x8 (&bf)[4][2][4],
        float (&xcur)[4][2][4], float (&xnxt)[4][2][4], float (&c8)[2][4],
        const float* vmsh, int lc, int quad, int wave, bool pf){
    bf16x8 af[4];
    #pragma unroll
    for(int kt=0;kt<4;kt++)
        af[kt] = *(const bf16x8*)&bufr[lc*HSTRIDE + kt*32 + quad*8];
    if(pf){
        #pragma unroll
        for(int gate=0;gate<4;gate++){
            #pragma unroll
            for(int ji=0;ji<2;ji++){
                #pragma unroll
                for(int r=0;r<4;r++)
                    xnxt[gate][ji][r] = pxg[(size_t)r*64*G4_ + (size_t)(l+1)*G4_ + gate*128 + ji*16];
            }
        }
    }
    f32x4 acc[8];
    #pragma unroll
    for(int a=0;a<8;a++) acc[a] = (f32x4){0.f,0.f,0.f,0.f};
    #pragma unroll
    for(int kt=0;kt<4;kt++){
        #pragma unroll
        for(int a=0;a<8;a++)
            acc[a] = __builtin_amdgcn_mfma_f32_16x16x32_bf16(af[kt], bf[a>>1][a&1][kt], acc[a], 0,0,0);
    }
    #pragma unroll
    for(int r=0;r<4;r++){
        float m = vmsh[(quad*4+r)*64 + l];
        #pragma unroll
        for(int ji=0;ji<2;ji++){
            float gi = acc[0+ji][r] + xcur[0][ji][r];
            float gf = acc[2+ji][r] + xcur[1][ji][r];
            float gg = acc[4+ji][r] + xcur[2][ji][r];
            float go = acc[6+ji][r] + xcur[3][ji][r];
            float c  = sigm(gf)*c8[ji][r] + sigm(gi)*ftanh(gg);
            float h  = sigm(go)*ftanh(c);
            c8[ji][r] = c;
            bufw[(quad*4+r)*HSTRIDE + wave*32 + ji*16 + lc] = f2bf(h);
            ph[(size_t)r*64*H_ + (size_t)l*H_ + ji*16] = h * m;
        }
    }
    LBAR();
}

__global__ __launch_bounds__(256,1) void k_lstm_mfma(const float* __restrict__ xg, const float* __restrict__ Whh,
                                                     const float* __restrict__ vmask, float* __restrict__ hout){
    __shared__ u16 hbuf[2][16*HSTRIDE];
    __shared__ float vmsh[16*64];
    int t = threadIdx.x;
    int wave = t >> 6, lane = t & 63;
    int quad = lane >> 4, lc = lane & 15;
    int b0 = blockIdx.x * 16;

    for(int i=t;i<16*HSTRIDE;i+=256) hbuf[0][i] = 0;
    for(int i=t;i<1024;i+=256) vmsh[i] = vmask[b0*64 + i];

    bf16x8 bf[4][2][4];
    #pragma unroll
    for(int gate=0;gate<4;gate++){
        #pragma unroll
        for(int ji=0;ji<2;ji++){
            int n = gate*128 + wave*32 + ji*16 + lc;
            const float* wr = Whh + (size_t)n*H_ + quad*8;
            #pragma unroll
            for(int kt=0;kt<4;kt++) bf[gate][ji][kt] = pack8(wr + kt*32);
        }
    }

    float c8[2][4];
    #pragma unroll
    for(int ji=0;ji<2;ji++){
        #pragma unroll
        for(int r=0;r<4;r++) c8[ji][r]=0.f;
    }

    const float* pxg = xg + ((size_t)(b0 + quad*4))*64*G4_ + wave*32 + lc;
    float* ph = hout + ((size_t)(b0 + quad*4))*64*H_ + wave*32 + lc;

    // prefetch xg for l=0
    float xgv0[4][2][4], xgv1[4][2][4];
    #pragma unroll
    for(int gate=0;gate<4;gate++){
        #pragma unroll
        for(int ji=0;ji<2;ji++){
            #pragma unroll
            for(int r=0;r<4;r++)
                xgv0[gate][ji][r] = pxg[(size_t)r*64*G4_ + gate*128 + ji*16];
        }
    }
    __syncthreads();

    for(int lb=0;lb<64;lb+=2){
        lstm_step(lb,   pxg, ph, hbuf[0], hbuf[1], bf, xgv0, xgv1, c8, vmsh, lc, quad, wave, true);
        lstm_step(lb+1, pxg, ph, hbuf[1], hbuf[0], bf, xgv1, xgv0, c8, vmsh, lc, quad, wave, (lb+1) < 63);
    }
}

// ---------------------------------------------------------------- hp = (h_prev @ W_proj^T) * m (MFMA)
__global__ __launch_bounds__(256,2) void k_hp(const float* __restrict__ h, const float* __restrict__ Wproj,
                                              const float* __restrict__ vmask, float* __restrict__ hp){
    __shared__ __align__(16) u16 abuf[16*AS];
    int t = threadIdx.x, wave = t >> 6, lane = t & 63, quad = lane >> 4, lc = lane & 15;
    int row0 = blockIdx.x * 16;
    #pragma unroll
    for(int i=0;i<8;i++){
        int flat = i*256 + t; int r = flat >> 7, e = flat & 127;
        int row = row0 + r;
        float hv = (row & 63) ? h[(size_t)(row-1)*H_ + e] : 0.f;
        abuf[r*AS + e] = f2bf(hv);
    }
    bf16x8 wfr[2][4];
    #pragma unroll
    for(int nt=0;nt<2;nt++){
        int n = wave*32 + nt*16 + lc;
        const float* wr = Wproj + (size_t)n*H_ + quad*8;
        #pragma unroll
        for(int kt=0;kt<4;kt++) wfr[nt][kt] = pack8(wr + kt*32);
    }
    __syncthreads();
    f32x4 acc[2];
    acc[0] = (f32x4){0.f,0.f,0.f,0.f}; acc[1] = (f32x4){0.f,0.f,0.f,0.f};
    #pragma unroll
    for(int kt=0;kt<4;kt++){
        bf16x8 af = *(const bf16x8*)&abuf[lc*AS + kt*32 + quad*8];
        acc[0] = __builtin_amdgcn_mfma_f32_16x16x32_bf16(af, wfr[0][kt], acc[0], 0,0,0);
        acc[1] = __builtin_amdgcn_mfma_f32_16x16x32_bf16(af, wfr[1][kt], acc[1], 0,0,0);
    }
    #pragma unroll
    for(int nt=0;nt<2;nt++){
        int n = wave*32 + nt*16 + lc;
        #pragma unroll
        for(int r=0;r<4;r++){
            int row = row0 + quad*4 + r;
            hp[(size_t)row*E_ + n] = acc[nt][r] * vmask[row];
        }
    }
}

// ---------------------------------------------------------------- logits
__global__ void k_logits(const float* __restrict__ h, const float* __restrict__ vmask,
                         const float* __restrict__ Wcls, const float* __restrict__ bcls, float* __restrict__ out){
    int b = blockIdx.x; int t = threadIdx.x;
    float s = vmask[b*64 + t];
    #pragma unroll
    for(int off=32;off;off>>=1) s += __shfl_down(s, off);
    s = __shfl(s, 0);
    int len = (int)(s + 0.5f); if(len < 1) len = 1;
    const float* hr = h + (size_t)(b*64 + len - 1)*H_;
    float val = hr[t]*Wcls[t] + hr[t+64]*Wcls[t+64];
    #pragma unroll
    for(int off=32;off;off>>=1) val += __shfl_down(val, off);
    if(t==0) out[b] = val + bcls[0];
}

// ---------------------------------------------------------------- diffusion loss via MFMA
__global__ __launch_bounds__(256,1) void k_diff_loss_mfma(const float* __restrict__ v, const float* __restrict__ hp,
        const float* __restrict__ eps, const int* __restrict__ tdiff, const float* __restrict__ vmask,
        const float* __restrict__ temb, const float* __restrict__ Wf, const float* __restrict__ bfu,
        const float* __restrict__ We1, const float* __restrict__ be1,
        const float* __restrict__ We2, const float* __restrict__ be2, float* __restrict__ lossacc){
    __shared__ float zbuf[16*ZS], hpbuf[16*ZS];
    __shared__ __align__(16) u16 xbuf[16*XS];
    __shared__ __align__(16) u16 y1buf[16*YS];
    __shared__ float wfsh[512];
    __shared__ float ssh[16][2], hpd[16][2];
    __shared__ float mrow[16]; __shared__ int trow[16];
    __shared__ float sabar[10];
    int row0 = blockIdx.x * 16; int t = threadIdx.x;
    int wave = t >> 6, lane = t & 63, quad = lane >> 4, lc = lane & 15;

    if(t==0){
        float p = 1.f;
        for(int k=0;k<10;k++){ float b = 1e-4f + (0.02f - 1e-4f)*k/9.f; p *= (1.f - b); sabar[k] = p; }
    }
    if(t < 16){
        int row = row0 + t; float m = vmask[row];
        mrow[t] = m; trow[t] = (m > 0.f) ? tdiff[row >> 6] : 1;
    }
    for(int i=t;i<512;i+=256) wfsh[i] = Wf[i];
    __syncthreads();
    #pragma unroll
    for(int i=0;i<8;i++){
        int flat = i*256 + t; int r = flat >> 7; int e = flat & 127; int row = row0 + r;
        float ab = sabar[trow[r]-1];
        zbuf[r*ZS + e] = (sqrtf(ab)*v[(size_t)row*E_ + e] + sqrtf(1.f - ab)*eps[(size_t)row*E_ + e]) * mrow[r];
        hpbuf[r*ZS + e] = hp[(size_t)row*E_ + e];
    }
    bf16x8 wf1[2][8], wf2[2][4];
    float be1v[2], be2v[2];
    #pragma unroll
    for(int nt=0;nt<2;nt++){
        int n = wave*32 + nt*16 + lc;
        be1v[nt] = be1[n]; be2v[nt] = be2[n];
        const float* w1 = We1 + (size_t)n*256 + quad*8;
        #pragma unroll
        for(int kt=0;kt<8;kt++) wf1[nt][kt] = pack8(w1 + kt*32);
        const float* w2 = We2 + (size_t)n*128 + quad*8;
        #pragma unroll
        for(int kt=0;kt<4;kt++) wf2[nt][kt] = pack8(w2 + kt*32);
    }
    __syncthreads();
    {
        int row = t >> 4, k = (t >> 3) & 1, sub = t & 7;
        float p = 0.f, q = 0.f;
        #pragma unroll
        for(int i=0;i<16;i++){
            p += hpbuf[row*ZS + sub*16 + i] * wfsh[k*256 + 128 + sub*16 + i];
            q += zbuf[row*ZS + sub*16 + i]  * wfsh[k*256 + sub*16 + i];
        }
        p += __shfl_down(p,4); p += __shfl_down(p,2); p += __shfl_down(p,1);
        q += __shfl_down(q,4); q += __shfl_down(q,2); q += __shfl_down(q,1);
        if(sub == 0){ hpd[row][k] = p + bfu[k]; ssh[row][k] = q; }
    }
    __syncthreads();
    {
        int row = t >> 4, c0 = (t & 15) * 16;
        float s0 = ssh[row][0] + hpd[row][0], s1 = ssh[row][1] + hpd[row][1];
        float a0 = 1.f/(1.f + __expf(s1 - s0)), a1 = 1.f - a0;
        int tt = trow[row];
        #pragma unroll
        for(int i=0;i<16;i++){
            int c = c0 + i;
            float val = (c < 128) ? (a0*zbuf[row*ZS + c] + a1*hpbuf[row*ZS + c])
                                  : temb[tt*E_ + (c - 128)];
            xbuf[row*XS + c] = f2bf(val);
        }
    }
    __syncthreads();
    f32x4 acc1[2];
    acc1[0] = (f32x4){0.f,0.f,0.f,0.f}; acc1[1] = (f32x4){0.f,0.f,0.f,0.f};
    #pragma unroll
    for(int kt=0;kt<8;kt++){
        bf16x8 af = *(const bf16x8*)&xbuf[lc*XS + kt*32 + quad*8];
        acc1[0] = __builtin_amdgcn_mfma_f32_16x16x32_bf16(af, wf1[0][kt], acc1[0], 0,0,0);
        acc1[1] = __builtin_amdgcn_mfma_f32_16x16x32_bf16(af, wf1[1][kt], acc1[1], 0,0,0);
    }
    #pragma unroll
    for(int nt=0;nt<2;nt++){
        #pragma unroll
        for(int r=0;r<4;r++)
            y1buf[(quad*4+r)*YS + wave*32 + nt*16 + lc] = f2bf(fmaxf(acc1[nt][r] + be1v[nt], 0.f));
    }
    __syncthreads();
    f32x4 acc2[2];
    acc2[0] = (f32x4){0.f,0.f,0.f,0.f}; acc2[1] = (f32x4){0.f,0.f,0.f,0.f};
    #pragma unroll
    for(int kt=0;kt<4;kt++){
        bf16x8 af = *(const bf16x8*)&y1buf[lc*YS + kt*32 + quad*8];
        acc2[0] = __builtin_amdgcn_mfma_f32_16x16x32_bf16(af, wf2[0][kt], acc2[0], 0,0,0);
        acc2[1] = __builtin_amdgcn_mfma_f32_16x16x32_bf16(af, wf2[1][kt], acc2[1], 0,0,0);
    }
    float lp = 0.f;
    #pragma unroll
    for(int nt=0;nt<2;nt++){
        int n = wave*32 + nt*16 + lc;
        #pragma unroll
        for(int r=0;r<4;r++){
            int m = quad*4 + r;
            float d = (acc2[nt][r] + be2v[nt]) - eps[(size_t)(row0+m)*E_ + n];
            lp += d*d*mrow[m];
        }
    }
    #pragma unroll
    for(int off=32;off;off>>=1) lp += __shfl_down(lp, off);
    if(lane == 0) atomicAdd(lossacc, lp);
}

// ---------------------------------------------------------------- reverse diffusion via MFMA
__global__ __launch_bounds__(256,1) void k_reverse_mfma(const float* __restrict__ hp, const float* __restrict__ z0,
        const float* __restrict__ noise, const float* __restrict__ vmask, const float* __restrict__ temb,
        const float* __restrict__ Wf, const float* __restrict__ bfu,
        const float* __restrict__ We1, const float* __restrict__ be1,
        const float* __restrict__ We2, const float* __restrict__ be2, float* __restrict__ vsyn){
    __shared__ float zbuf[16*ZS], hpbuf[16*ZS];
    __shared__ __align__(16) u16 xbuf[16*XS];
    __shared__ __align__(16) u16 y1buf[16*YS];
    __shared__ float wfsh[512];
    __shared__ float ssh[16][2], hpd[16][2];
    __shared__ float mrow[16];
    __shared__ float sbeta[10], sabar[10];
    int row0 = blockIdx.x * 16; int t = threadIdx.x;
    int wave = t >> 6, lane = t & 63, quad = lane >> 4, lc = lane & 15;

    if(t==0){
        float p = 1.f;
        for(int k=0;k<10;k++){ float b = 1e-4f + (0.02f - 1e-4f)*k/9.f; sbeta[k] = b; p *= (1.f - b); sabar[k] = p; }
    }
    if(t < 16) mrow[t] = vmask[row0 + t];
    for(int i=t;i<512;i+=256) wfsh[i] = Wf[i];
    #pragma unroll
    for(int i=0;i<8;i++){
        int flat = i*256 + t; int r = flat >> 7; int e = flat & 127; int row = row0 + r;
        zbuf[r*ZS + e]  = z0[(size_t)row*E_ + e];
        hpbuf[r*ZS + e] = hp[(size_t)row*E_ + e];
    }
    bf16x8 wf1[2][8], wf2[2][4];
    float be1v[2], be2v[2];
    #pragma unroll
    for(int nt=0;nt<2;nt++){
        int n = wave*32 + nt*16 + lc;
        be1v[nt] = be1[n]; be2v[nt] = be2[n];
        const float* w1 = We1 + (size_t)n*256 + quad*8;
        #pragma unroll
        for(int kt=0;kt<8;kt++) wf1[nt][kt] = pack8(w1 + kt*32);
        const float* w2 = We2 + (size_t)n*128 + quad*8;
        #pragma unroll
        for(int kt=0;kt<4;kt++) wf2[nt][kt] = pack8(w2 + kt*32);
    }
    __syncthreads();
    {
        int row = t >> 4, k = (t >> 3) & 1, sub = t & 7;
        float p = 0.f;
        #pragma unroll
        for(int i=0;i<16;i++)
            p += hpbuf[row*ZS + sub*16 + i] * wfsh[k*256 + 128 + sub*16 + i];
        p += __shfl_down(p,4); p += __shfl_down(p,2); p += __shfl_down(p,1);
        if(sub == 0) hpd[row][k] = p + bfu[k];
    }
    __syncthreads();

    for(int s=0;s<10;s++){
        int kk = 10 - s;
        {
            int row = t >> 4, k = (t >> 3) & 1, sub = t & 7;
            float q = 0.f;
            #pragma unroll
            for(int i=0;i<16;i++)
                q += zbuf[row*ZS + sub*16 + i] * wfsh[k*256 + sub*16 + i];
            q += __shfl_down(q,4); q += __shfl_down(q,2); q += __shfl_down(q,1);
            if(sub == 0) ssh[row][k] = q + hpd[row][k];
        }
        __syncthreads();
        {
            int row = t >> 4, c0 = (t & 15) * 16;
            float s0 = ssh[row][0], s1 = ssh[row][1];
            float a0 = 1.f/(1.f + __expf(s1 - s0)), a1 = 1.f - a0;
            int tt = (mrow[row] > 0.f) ? kk : 1;
            #pragma unroll
            for(int i=0;i<16;i++){
                int c = c0 + i;
                float val = (c < 128) ? (a0*zbuf[row*ZS + c] + a1*hpbuf[row*ZS + c])
                                      : temb[tt*E_ + (c - 128)];
                xbuf[row*XS + c] = f2bf(val);
            }
        }
        __syncthreads();
        f32x4 acc1[2];
        acc1[0] = (f32x4){0.f,0.f,0.f,0.f}; acc1[1] = (f32x4){0.f,0.f,0.f,0.f};
        #pragma unroll
        for(int kt=0;kt<8;kt++){
            bf16x8 af = *(const bf16x8*)&xbuf[lc*XS + kt*32 + quad*8];
            acc1[0] = __builtin_amdgcn_mfma_f32_16x16x32_bf16(af, wf1[0][kt], acc1[0], 0,0,0);
            acc1[1] = __builtin_amdgcn_mfma_f32_16x16x32_bf16(af, wf1[1][kt], acc1[1], 0,0,0);
        }
        #pragma unroll
        for(int nt=0;nt<2;nt++){
            #pragma unroll
            for(int r=0;r<4;r++)
                y1buf[(quad*4+r)*YS + wave*32 + nt*16 + lc] = f2bf(fmaxf(acc1[nt][r] + be1v[nt], 0.f));
        }
        __syncthreads();
        f32x4 acc2[2];
        acc2[0] = (f32x4){0.f,0.f,0.f,0.f}; acc2[1] = (f32x4){0.f,0.f,0.f,0.f};
        #pragma unroll
        for(int kt=0;kt<4;kt++){
            bf16x8 af = *(const bf16x8*)&y1buf[lc*YS + kt*32 + quad*8];
            acc2[0] = __builtin_amdgcn_mfma_f32_16x16x32_bf16(af, wf2[0][kt], acc2[0], 0,0,0);
            acc2[1] = __builtin_amdgcn_mfma_f32_16x16x32_bf16(af, wf2[1][kt], acc2[1], 0,0,0);
        }
        float beta = sbeta[kk-1];
        float c1 = beta / sqrtf(1.f - sabar[kk-1]);
        float c2 = 1.f / sqrtf(1.f - beta);
        float sb = sqrtf(beta);
        #pragma unroll
        for(int nt=0;nt<2;nt++){
            int n = wave*32 + nt*16 + lc;
            #pragma unroll
            for(int r=0;r<4;r++){
                int m = quad*4 + r;
                float e = acc2[nt][r] + be2v[nt];
                float z = zbuf[m*ZS + n];
                float mean = (z - c1*e) * c2;
                float nz = noise[((size_t)s*NROW + row0 + m)*E_ + n];
                float znew = (kk > 1) ? (mean + sb*nz) : mean;
                zbuf[m*ZS + n] = znew * mrow[m];
            }
        }
        __syncthreads();
    }
    {
        int row = t >> 4, c0 = (t & 15) * 16;
        if(c0 < 128){
            #pragma unroll
            for(int i=0;i<16;i++)
                vsyn[(size_t)(row0+row)*E_ + c0 + i] = zbuf[row*ZS + c0 + i];
        }
    }
}

// ---------------------------------------------------------------- loss finalize
__global__ void k_finalize(const float* __restrict__ lossacc, const float* __restrict__ vmask, float* __restrict__ out){
    __shared__ float rb[4];
    int t = threadIdx.x;
    float s = 0.f;
    for(int i=t;i<NROW;i+=256) s += vmask[i];
    #pragma unroll
    for(int off=32;off;off>>=1) s += __shfl_down(s, off);
    if((t & 63) == 0) rb[t >> 6] = s;
    __syncthreads();
    if(t == 0){
        float denom = rb[0]+rb[1]+rb[2]+rb[3];
        if(denom < 1.f) denom = 1.f;
        out[256] = lossacc[0] / denom;
    }
}

extern "C" void kernel_launch(void* const* d_in, const int* in_sizes, int n_in,
                              void* d_out, int out_size, void* d_ws, size_t ws_size,
                              hipStream_t stream){
    const float* px    = (const float*)d_in[0];
    const float* vmask = (const float*)d_in[1];
    const int*   bins  = (const int*)d_in[2];
    const int*   tdiff = (const int*)d_in[3];
    const float* eps   = (const float*)d_in[4];
    const float* z0    = (const float*)d_in[5];
    const float* noise = (const float*)d_in[6];
    const float* Wv    = (const float*)d_in[7];
    const float* bemb  = (const float*)d_in[8];
    const float* Wih   = (const float*)d_in[9];
    const float* Whh   = (const float*)d_in[10];
    const float* bih   = (const float*)d_in[11];
    const float* bhh   = (const float*)d_in[12];
    const float* Wcls  = (const float*)d_in[13];
    const float* bcls  = (const float*)d_in[14];
    const float* Wproj = (const float*)d_in[15];
    const float* temb  = (const float*)d_in[16];
    const float* Wf    = (const float*)d_in[17];
    const float* bfu   = (const float*)d_in[18];
    const float* We1   = (const float*)d_in[19];
    const float* be1   = (const float*)d_in[20];
    const float* We2   = (const float*)d_in[21];
    const float* be2   = (const float*)d_in[22];
    float* out = (float*)d_out;

    float* ws      = (float*)d_ws;
    float* WT      = ws;
    float* v       = ws + 1048576;
    float* xg      = ws + 2097152;
    float* h       = ws + 6291456;
    float* hp      = ws + 7340032;
    float* vsyn    = ws + 8388608;
    float* lossacc = ws + 9437184;

    hipLaunchKernelGGL(k_transpose_wv, dim3(V_/16), dim3(256), 0, stream, Wv, WT);
    hipLaunchKernelGGL(k_visit_embed, dim3(NROW), dim3(256), 0, stream, px, vmask, bins, bemb, WT, v);
    hipLaunchKernelGGL(k_gemm_xg, dim3(NROW/16), dim3(256), 0, stream, v, Wih, bih, bhh, xg);
    hipLaunchKernelGGL(k_lstm_mfma, dim3(B_/16), dim3(256), 0, stream, xg, Whh, vmask, h);
    hipLaunchKernelGGL(k_logits, dim3(B_), dim3(64), 0, stream, h, vmask, Wcls, bcls, out);
    hipLaunchKernelGGL(k_hp, dim3(NROW/16), dim3(256), 0, stream, h, Wproj, vmask, hp);
    hipMemsetAsync(lossacc, 0, sizeof(float), stream);
    hipLaunchKernelGGL(k_diff_loss_mfma, dim3(NROW/16), dim3(256), 0, stream,
                       v, hp, eps, tdiff, vmask, temb, Wf, bfu, We1, be1, We2, be2, lossacc);
    hipLaunchKernelGGL(k_reverse_mfma, dim3(NROW/16), dim3(256), 0, stream,
                       hp, z0, noise, vmask, temb, Wf, bfu, We1, be1, We2, be2, vsyn);
    hipLaunchKernelGGL(k_gemm_xg, dim3(NROW/16), dim3(256), 0, stream, vsyn, Wih, bih, bhh, xg);
    hipLaunchKernelGGL(k_lstm_mfma, dim3(B_/16), dim3(256), 0, stream, xg, Whh, vmask, h);
    hipLaunchKernelGGL(k_logits, dim3(B_), dim3(64), 0, stream, h, vmask, Wcls, bcls, out + 128);
    hipLaunchKernelGGL(k_finalize, dim3(1), dim3(256), 0, stream, lossacc, vmask, out);
}

// Round 6
// 828.664 us; speedup vs baseline: 2.2659x; 1.0882x over previous
//
#include <hip/hip_runtime.h>

#define B_ 128
#define L_ 64
#define V_ 8192
#define E_ 128
#define H_ 128
#define G4_ 512
#define NROW (B_*L_)
#define HSTRIDE 136
#define AS 136
#define XS 264
#define YS 136
#define ZS 132

typedef unsigned short u16;
typedef __attribute__((ext_vector_type(8))) short bf16x8;
typedef __attribute__((ext_vector_type(4))) float f32x4;

__device__ __forceinline__ float sigm(float x){ return 1.f/(1.f + __expf(-x)); }
__device__ __forceinline__ float ftanh(float x){ float e = __expf(2.f*x); return 1.f - 2.f/(e + 1.f); }
__device__ __forceinline__ u16 f2bf(float f){
    union { unsigned int i; float f; } x; x.f = f;
    unsigned int r = x.i + 0x7fff + ((x.i >> 16) & 1);
    return (u16)(r >> 16);
}
// raw barrier: LDS-only sync, no vmcnt drain
#define LBAR() asm volatile("s_waitcnt lgkmcnt(0)\ns_barrier" ::: "memory")

__device__ __forceinline__ bf16x8 pack8(const float* p){
    const float4* q = (const float4*)p;
    float4 a = q[0], b = q[1];
    bf16x8 f;
    f[0]=(short)f2bf(a.x); f[1]=(short)f2bf(a.y); f[2]=(short)f2bf(a.z); f[3]=(short)f2bf(a.w);
    f[4]=(short)f2bf(b.x); f[5]=(short)f2bf(b.y); f[6]=(short)f2bf(b.z); f[7]=(short)f2bf(b.w);
    return f;
}

// ---------------------------------------------------------------- transpose W_visit [E,V] -> WT [V,E]
__global__ __launch_bounds__(256) void k_transpose_wv(const float* __restrict__ Wv, float* __restrict__ WT){
    __shared__ float tile[16][129];
    int v0 = blockIdx.x * 16;
    int t = threadIdx.x;
    #pragma unroll
    for(int i=0;i<8;i++){
        int idx = i*256 + t; int e = idx >> 4; int vv = idx & 15;
        tile[vv][e] = Wv[(size_t)e*V_ + v0 + vv];
    }
    __syncthreads();
    #pragma unroll
    for(int i=0;i<8;i++){
        int idx = i*256 + t; int vv = idx >> 7; int e = idx & 127;
        WT[(size_t)(v0+vv)*E_ + e] = tile[vv][e];
    }
}

// ---------------------------------------------------------------- v = (x @ Wv^T + bin_embed[delta]) * m
__global__ __launch_bounds__(256) void k_visit_embed(const float* __restrict__ px, const float* __restrict__ vmask,
                                                     const int* __restrict__ bins, const float* __restrict__ bemb,
                                                     const float* __restrict__ WT, float* __restrict__ v){
    __shared__ int idxs[512];
    __shared__ int cnt;
    __shared__ int dsh;
    __shared__ float msh;
    __shared__ float4 red[8][32];
    int row = blockIdx.x; int l = row & 63;
    int t = threadIdx.x;
    if(t==0){
        cnt = 0;
        float m = vmask[row];
        int d = 0;
        if(l > 0){ d = bins[row] - bins[row-1]; d = d < 0 ? 0 : (d > 513 ? 513 : d); }
        if(!(m > 0.f)) d = 0;
        dsh = d; msh = m;
    }
    __syncthreads();
    const uint4* xr4 = (const uint4*)(px + (size_t)row * V_);
    for(int i=t;i<2048;i+=256){
        uint4 u = xr4[i];
        unsigned int w[4] = {u.x,u.y,u.z,u.w};
        #pragma unroll
        for(int j=0;j<4;j++){
            if(w[j]){ int p = atomicAdd(&cnt,1); if(p<512) idxs[p] = i*4 + j; }
        }
    }
    __syncthreads();
    int n = cnt; if(n > 512) n = 512;
    // parallel gather: 8 j-groups x 32 threads x float4
    int eq = t & 31, jg = t >> 5;
    float4 a4 = {0.f,0.f,0.f,0.f};
    for(int j=jg;j<n;j+=8){
        const float4* wr = (const float4*)(WT + (size_t)idxs[j]*E_);
        float4 wv = wr[eq];
        a4.x += wv.x; a4.y += wv.y; a4.z += wv.z; a4.w += wv.w;
    }
    red[jg][eq] = a4;
    __syncthreads();
    if(t < 32){
        float4 s = red[0][t];
        #pragma unroll
        for(int g=1;g<8;g++){
            float4 r = red[g][t];
            s.x += r.x; s.y += r.y; s.z += r.z; s.w += r.w;
        }
        const float4* bp = (const float4*)(bemb + dsh*E_);
        float4 bv = bp[t];
        float m = msh;
        float4 o;
        o.x = (s.x + bv.x)*m; o.y = (s.y + bv.y)*m; o.z = (s.z + bv.z)*m; o.w = (s.w + bv.w)*m;
        ((float4*)(v + (size_t)row*E_))[t] = o;
    }
}

// ---------------------------------------------------------------- xg = A @ W_ih^T + b_ih + b_hh (MFMA)
__global__ __launch_bounds__(256,2) void k_gemm_xg(const float* __restrict__ A, const float* __restrict__ Wih,
                                                   const float* __restrict__ bih, const float* __restrict__ bhh,
                                                   float* __restrict__ xg){
    __shared__ __align__(16) u16 abuf[16*AS];
    int t = threadIdx.x, wave = t >> 6, lane = t & 63, quad = lane >> 4, lc = lane & 15;
    int row0 = blockIdx.x * 16;
    #pragma unroll
    for(int i=0;i<8;i++){
        int flat = i*256 + t; int r = flat >> 7, e = flat & 127;
        abuf[r*AS + e] = f2bf(A[(size_t)(row0+r)*E_ + e]);
    }
    bf16x8 wfr[8][4]; float bb[8];
    #pragma unroll
    for(int nt=0;nt<8;nt++){
        int n = wave*128 + nt*16 + lc;
        bb[nt] = bih[n] + bhh[n];
        const float* wr = Wih + (size_t)n*E_ + quad*8;
        #pragma unroll
        for(int kt=0;kt<4;kt++) wfr[nt][kt] = pack8(wr + kt*32);
    }
    __syncthreads();
    f32x4 acc[8];
    #pragma unroll
    for(int nt=0;nt<8;nt++) acc[nt] = (f32x4){0.f,0.f,0.f,0.f};
    #pragma unroll
    for(int kt=0;kt<4;kt++){
        bf16x8 af = *(const bf16x8*)&abuf[lc*AS + kt*32 + quad*8];
        #pragma unroll
        for(int nt=0;nt<8;nt++)
            acc[nt] = __builtin_amdgcn_mfma_f32_16x16x32_bf16(af, wfr[nt][kt], acc[nt], 0,0,0);
    }
    #pragma unroll
    for(int nt=0;nt<8;nt++){
        int n = wave*128 + nt*16 + lc;
        #pragma unroll
        for(int r=0;r<4;r++)
            xg[(size_t)(row0 + quad*4 + r)*G4_ + n] = acc[nt][r] + bb[nt];
    }
}

// ---------------------------------------------------------------- LSTM via MFMA: 512 thr (2 waves/SIMD), dbuf, prefetch
__device__ __forceinline__ void lstm_step(int l, const float* pxg, float* ph,
        const u16* bufr, u16* bufw, const bf16x8 (&bf)[4][4],
        float (&xcur)[4][4], float (&xnxt)[4][4], float (&c4)[4],
        const float* vmsh, int lc, int quad, int wave, bool pf){
    bf16x8 af[4];
    #pragma unroll
    for(int kt=0;kt<4;kt++)
        af[kt] = *(const bf16x8*)&bufr[lc*HSTRIDE + kt*32 + quad*8];
    if(pf){
        #pragma unroll
        for(int gate=0;gate<4;gate++){
            #pragma unroll
            for(int r=0;r<4;r++)
                xnxt[gate][r] = pxg[(size_t)r*64*G4_ + (size_t)(l+1)*G4_ + gate*128];
        }
    }
    f32x4 acc[4];
    #pragma unroll
    for(int a=0;a<4;a++) acc[a] = (f32x4){0.f,0.f,0.f,0.f};
    #pragma unroll
    for(int kt=0;kt<4;kt++){
        #pragma unroll
        for(int a=0;a<4;a++)
            acc[a] = __builtin_amdgcn_mfma_f32_16x16x32_bf16(af[kt], bf[a][kt], acc[a], 0,0,0);
    }
    #pragma unroll
    for(int r=0;r<4;r++){
        float m = vmsh[(quad*4+r)*64 + l];
        float gi = acc[0][r] + xcur[0][r];
        float gf = acc[1][r] + xcur[1][r];
        float gg = acc[2][r] + xcur[2][r];
        float go = acc[3][r] + xcur[3][r];
        float c  = sigm(gf)*c4[r] + sigm(gi)*ftanh(gg);
        float h  = sigm(go)*ftanh(c);
        c4[r] = c;
        bufw[(quad*4+r)*HSTRIDE + wave*16 + lc] = f2bf(h);
        ph[(size_t)r*64*H_ + (size_t)l*H_] = h * m;
    }
    LBAR();
}

__global__ __launch_bounds__(512,2) void k_lstm_mfma(const float* __restrict__ xg, const float* __restrict__ Whh,
                                                     const float* __restrict__ vmask, float* __restrict__ hout){
    __shared__ u16 hbuf[2][16*HSTRIDE];
    __shared__ float vmsh[16*64];
    int t = threadIdx.x;
    int wave = t >> 6, lane = t & 63;
    int quad = lane >> 4, lc = lane & 15;
    int b0 = blockIdx.x * 16;

    for(int i=t;i<16*HSTRIDE;i+=512) hbuf[0][i] = 0;
    for(int i=t;i<1024;i+=512) vmsh[i] = vmask[b0*64 + i];

    // wave owns cols n = gate*128 + wave*16 + lc, for all 4 gates
    bf16x8 bf[4][4];
    #pragma unroll
    for(int gate=0;gate<4;gate++){
        int n = gate*128 + wave*16 + lc;
        const float* wr = Whh + (size_t)n*H_ + quad*8;
        #pragma unroll
        for(int kt=0;kt<4;kt++) bf[gate][kt] = pack8(wr + kt*32);
    }

    float c4[4] = {0.f,0.f,0.f,0.f};

    const float* pxg = xg + ((size_t)(b0 + quad*4))*64*G4_ + wave*16 + lc;
    float* ph = hout + ((size_t)(b0 + quad*4))*64*H_ + wave*16 + lc;

    float xgv0[4][4], xgv1[4][4];
    #pragma unroll
    for(int gate=0;gate<4;gate++){
        #pragma unroll
        for(int r=0;r<4;r++)
            xgv0[gate][r] = pxg[(size_t)r*64*G4_ + gate*128];
    }
    __syncthreads();

    for(int lb=0;lb<64;lb+=2){
        lstm_step(lb,   pxg, ph, hbuf[0], hbuf[1], bf, xgv0, xgv1, c4, vmsh, lc, quad, wave, true);
        lstm_step(lb+1, pxg, ph, hbuf[1], hbuf[0], bf, xgv1, xgv0, c4, vmsh, lc, quad, wave, (lb+1) < 63);
    }
}

// ---------------------------------------------------------------- hp = (h_prev @ W_proj^T) * m (MFMA)
__global__ __launch_bounds__(256,2) void k_hp(const float* __restrict__ h, const float* __restrict__ Wproj,
                                              const float* __restrict__ vmask, float* __restrict__ hp){
    __shared__ __align__(16) u16 abuf[16*AS];
    int t = threadIdx.x, wave = t >> 6, lane = t & 63, quad = lane >> 4, lc = lane & 15;
    int row0 = blockIdx.x * 16;
    #pragma unroll
    for(int i=0;i<8;i++){
        int flat = i*256 + t; int r = flat >> 7, e = flat & 127;
        int row = row0 + r;
        float hv = (row & 63) ? h[(size_t)(row-1)*H_ + e] : 0.f;
        abuf[r*AS + e] = f2bf(hv);
    }
    bf16x8 wfr[2][4];
    #pragma unroll
    for(int nt=0;nt<2;nt++){
        int n = wave*32 + nt*16 + lc;
        const float* wr = Wproj + (size_t)n*H_ + quad*8;
        #pragma unroll
        for(int kt=0;kt<4;kt++) wfr[nt][kt] = pack8(wr + kt*32);
    }
    __syncthreads();
    f32x4 acc[2];
    acc[0] = (f32x4){0.f,0.f,0.f,0.f}; acc[1] = (f32x4){0.f,0.f,0.f,0.f};
    #pragma unroll
    for(int kt=0;kt<4;kt++){
        bf16x8 af = *(const bf16x8*)&abuf[lc*AS + kt*32 + quad*8];
        acc[0] = __builtin_amdgcn_mfma_f32_16x16x32_bf16(af, wfr[0][kt], acc[0], 0,0,0);
        acc[1] = __builtin_amdgcn_mfma_f32_16x16x32_bf16(af, wfr[1][kt], acc[1], 0,0,0);
    }
    #pragma unroll
    for(int nt=0;nt<2;nt++){
        int n = wave*32 + nt*16 + lc;
        #pragma unroll
        for(int r=0;r<4;r++){
            int row = row0 + quad*4 + r;
            hp[(size_t)row*E_ + n] = acc[nt][r] * vmask[row];
        }
    }
}

// ---------------------------------------------------------------- logits
__global__ void k_logits(const float* __restrict__ h, const float* __restrict__ vmask,
                         const float* __restrict__ Wcls, const float* __restrict__ bcls, float* __restrict__ out){
    int b = blockIdx.x; int t = threadIdx.x;
    float s = vmask[b*64 + t];
    #pragma unroll
    for(int off=32;off;off>>=1) s += __shfl_down(s, off);
    s = __shfl(s, 0);
    int len = (int)(s + 0.5f); if(len < 1) len = 1;
    const float* hr = h + (size_t)(b*64 + len - 1)*H_;
    float val = hr[t]*Wcls[t] + hr[t+64]*Wcls[t+64];
    #pragma unroll
    for(int off=32;off;off>>=1) val += __shfl_down(val, off);
    if(t==0) out[b] = val + bcls[0];
}

// ---------------------------------------------------------------- diffusion loss via MFMA -> per-block partials
__global__ __launch_bounds__(256,2) void k_diff_loss_mfma(const float* __restrict__ v, const float* __restrict__ hp,
        const float* __restrict__ eps, const int* __restrict__ tdiff, const float* __restrict__ vmask,
        const float* __restrict__ temb, const float* __restrict__ Wf, const float* __restrict__ bfu,
        const float* __restrict__ We1, const float* __restrict__ be1,
        const float* __restrict__ We2, const float* __restrict__ be2, float* __restrict__ partial){
    __shared__ float zbuf[16*ZS], hpbuf[16*ZS];
    __shared__ __align__(16) u16 xbuf[16*XS];
    __shared__ __align__(16) u16 y1buf[16*YS];
    __shared__ float wfsh[512];
    __shared__ float ssh[16][2], hpd[16][2];
    __shared__ float mrow[16]; __shared__ int trow[16];
    __shared__ float sabar[10];
    __shared__ float rb[4];
    int row0 = blockIdx.x * 16; int t = threadIdx.x;
    int wave = t >> 6, lane = t & 63, quad = lane >> 4, lc = lane & 15;

    if(t==0){
        float p = 1.f;
        for(int k=0;k<10;k++){ float b = 1e-4f + (0.02f - 1e-4f)*k/9.f; p *= (1.f - b); sabar[k] = p; }
    }
    if(t < 16){
        int row = row0 + t; float m = vmask[row];
        mrow[t] = m; trow[t] = (m > 0.f) ? tdiff[row >> 6] : 1;
    }
    for(int i=t;i<512;i+=256) wfsh[i] = Wf[i];
    __syncthreads();
    #pragma unroll
    for(int i=0;i<8;i++){
        int flat = i*256 + t; int r = flat >> 7; int e = flat & 127; int row = row0 + r;
        float ab = sabar[trow[r]-1];
        zbuf[r*ZS + e] = (sqrtf(ab)*v[(size_t)row*E_ + e] + sqrtf(1.f - ab)*eps[(size_t)row*E_ + e]) * mrow[r];
        hpbuf[r*ZS + e] = hp[(size_t)row*E_ + e];
    }
    bf16x8 wf1[2][8], wf2[2][4];
    float be1v[2], be2v[2];
    #pragma unroll
    for(int nt=0;nt<2;nt++){
        int n = wave*32 + nt*16 + lc;
        be1v[nt] = be1[n]; be2v[nt] = be2[n];
        const float* w1 = We1 + (size_t)n*256 + quad*8;
        #pragma unroll
        for(int kt=0;kt<8;kt++) wf1[nt][kt] = pack8(w1 + kt*32);
        const float* w2 = We2 + (size_t)n*128 + quad*8;
        #pragma unroll
        for(int kt=0;kt<4;kt++) wf2[nt][kt] = pack8(w2 + kt*32);
    }
    __syncthreads();
    {
        int row = t >> 4, k = (t >> 3) & 1, sub = t & 7;
        float p = 0.f, q = 0.f;
        #pragma unroll
        for(int i=0;i<16;i++){
            p += hpbuf[row*ZS + sub*16 + i] * wfsh[k*256 + 128 + sub*16 + i];
            q += zbuf[row*ZS + sub*16 + i]  * wfsh[k*256 + sub*16 + i];
        }
        p += __shfl_down(p,4); p += __shfl_down(p,2); p += __shfl_down(p,1);
        q += __shfl_down(q,4); q += __shfl_down(q,2); q += __shfl_down(q,1);
        if(sub == 0){ hpd[row][k] = p + bfu[k]; ssh[row][k] = q; }
    }
    __syncthreads();
    {
        int row = t >> 4, c0 = (t & 15) * 16;
        float s0 = ssh[row][0] + hpd[row][0], s1 = ssh[row][1] + hpd[row][1];
        float a0 = 1.f/(1.f + __expf(s1 - s0)), a1 = 1.f - a0;
        int tt = trow[row];
        #pragma unroll
        for(int i=0;i<16;i++){
            int c = c0 + i;
            float val = (c < 128) ? (a0*zbuf[row*ZS + c] + a1*hpbuf[row*ZS + c])
                                  : temb[tt*E_ + (c - 128)];
            xbuf[row*XS + c] = f2bf(val);
        }
    }
    __syncthreads();
    f32x4 acc1[2];
    acc1[0] = (f32x4){0.f,0.f,0.f,0.f}; acc1[1] = (f32x4){0.f,0.f,0.f,0.f};
    #pragma unroll
    for(int kt=0;kt<8;kt++){
        bf16x8 af = *(const bf16x8*)&xbuf[lc*XS + kt*32 + quad*8];
        acc1[0] = __builtin_amdgcn_mfma_f32_16x16x32_bf16(af, wf1[0][kt], acc1[0], 0,0,0);
        acc1[1] = __builtin_amdgcn_mfma_f32_16x16x32_bf16(af, wf1[1][kt], acc1[1], 0,0,0);
    }
    #pragma unroll
    for(int nt=0;nt<2;nt++){
        #pragma unroll
        for(int r=0;r<4;r++)
            y1buf[(quad*4+r)*YS + wave*32 + nt*16 + lc] = f2bf(fmaxf(acc1[nt][r] + be1v[nt], 0.f));
    }
    __syncthreads();
    f32x4 acc2[2];
    acc2[0] = (f32x4){0.f,0.f,0.f,0.f}; acc2[1] = (f32x4){0.f,0.f,0.f,0.f};
    #pragma unroll
    for(int kt=0;kt<4;kt++){
        bf16x8 af = *(const bf16x8*)&y1buf[lc*YS + kt*32 + quad*8];
        acc2[0] = __builtin_amdgcn_mfma_f32_16x16x32_bf16(af, wf2[0][kt], acc2[0], 0,0,0);
        acc2[1] = __builtin_amdgcn_mfma_f32_16x16x32_bf16(af, wf2[1][kt], acc2[1], 0,0,0);
    }
    float lp = 0.f;
    #pragma unroll
    for(int nt=0;nt<2;nt++){
        int n = wave*32 + nt*16 + lc;
        #pragma unroll
        for(int r=0;r<4;r++){
            int m = quad*4 + r;
            float d = (acc2[nt][r] + be2v[nt]) - eps[(size_t)(row0+m)*E_ + n];
            lp += d*d*mrow[m];
        }
    }
    #pragma unroll
    for(int off=32;off;off>>=1) lp += __shfl_down(lp, off);
    if(lane == 0) rb[wave] = lp;
    __syncthreads();
    if(t == 0) partial[blockIdx.x] = rb[0]+rb[1]+rb[2]+rb[3];
}

// ---------------------------------------------------------------- reverse diffusion via MFMA
__global__ __launch_bounds__(256,2) void k_reverse_mfma(const float* __restrict__ hp, const float* __restrict__ z0,
        const float* __restrict__ noise, const float* __restrict__ vmask, const float* __restrict__ temb,
        const float* __restrict__ Wf, const float* __restrict__ bfu,
        const float* __restrict__ We1, const float* __restrict__ be1,
        const float* __restrict__ We2, const float* __restrict__ be2, float* __restrict__ vsyn){
    __shared__ float zbuf[16*ZS], hpbuf[16*ZS];
    __shared__ __align__(16) u16 xbuf[16*XS];
    __shared__ __align__(16) u16 y1buf[16*YS];
    __shared__ float wfsh[512];
    __shared__ float ssh[16][2], hpd[16][2];
    __shared__ float mrow[16];
    __shared__ float sbeta[10], sabar[10];
    int row0 = blockIdx.x * 16; int t = threadIdx.x;
    int wave = t >> 6, lane = t & 63, quad = lane >> 4, lc = lane & 15;

    if(t==0){
        float p = 1.f;
        for(int k=0;k<10;k++){ float b = 1e-4f + (0.02f - 1e-4f)*k/9.f; sbeta[k] = b; p *= (1.f - b); sabar[k] = p; }
    }
    if(t < 16) mrow[t] = vmask[row0 + t];
    for(int i=t;i<512;i+=256) wfsh[i] = Wf[i];
    #pragma unroll
    for(int i=0;i<8;i++){
        int flat = i*256 + t; int r = flat >> 7; int e = flat & 127; int row = row0 + r;
        zbuf[r*ZS + e]  = z0[(size_t)row*E_ + e];
        hpbuf[r*ZS + e] = hp[(size_t)row*E_ + e];
    }
    bf16x8 wf1[2][8], wf2[2][4];
    float be1v[2], be2v[2];
    #pragma unroll
    for(int nt=0;nt<2;nt++){
        int n = wave*32 + nt*16 + lc;
        be1v[nt] = be1[n]; be2v[nt] = be2[n];
        const float* w1 = We1 + (size_t)n*256 + quad*8;
        #pragma unroll
        for(int kt=0;kt<8;kt++) wf1[nt][kt] = pack8(w1 + kt*32);
        const float* w2 = We2 + (size_t)n*128 + quad*8;
        #pragma unroll
        for(int kt=0;kt<4;kt++) wf2[nt][kt] = pack8(w2 + kt*32);
    }
    __syncthreads();
    {
        int row = t >> 4, k = (t >> 3) & 1, sub = t & 7;
        float p = 0.f;
        #pragma unroll
        for(int i=0;i<16;i++)
            p += hpbuf[row*ZS + sub*16 + i] * wfsh[k*256 + 128 + sub*16 + i];
        p += __shfl_down(p,4); p += __shfl_down(p,2); p += __shfl_down(p,1);
        if(sub == 0) hpd[row][k] = p + bfu[k];
    }
    __syncthreads();

    for(int s=0;s<10;s++){
        int kk = 10 - s;
        {
            int row = t >> 4, k = (t >> 3) & 1, sub = t & 7;
            float q = 0.f;
            #pragma unroll
            for(int i=0;i<16;i++)
                q += zbuf[row*ZS + sub*16 + i] * wfsh[k*256 + sub*16 + i];
            q += __shfl_down(q,4); q += __shfl_down(q,2); q += __shfl_down(q,1);
            if(sub == 0) ssh[row][k] = q + hpd[row][k];
        }
        __syncthreads();
        {
            int row = t >> 4, c0 = (t & 15) * 16;
            float s0 = ssh[row][0], s1 = ssh[row][1];
            float a0 = 1.f/(1.f + __expf(s1 - s0)), a1 = 1.f - a0;
            int tt = (mrow[row] > 0.f) ? kk : 1;
            #pragma unroll
            for(int i=0;i<16;i++){
                int c = c0 + i;
                float val = (c < 128) ? (a0*zbuf[row*ZS + c] + a1*hpbuf[row*ZS + c])
                                      : temb[tt*E_ + (c - 128)];
                xbuf[row*XS + c] = f2bf(val);
            }
        }
        __syncthreads();
        f32x4 acc1[2];
        acc1[0] = (f32x4){0.f,0.f,0.f,0.f}; acc1[1] = (f32x4){0.f,0.f,0.f,0.f};
        #pragma unroll
        for(int kt=0;kt<8;kt++){
            bf16x8 af = *(const bf16x8*)&xbuf[lc*XS + kt*32 + quad*8];
            acc1[0] = __builtin_amdgcn_mfma_f32_16x16x32_bf16(af, wf1[0][kt], acc1[0], 0,0,0);
            acc1[1] = __builtin_amdgcn_mfma_f32_16x16x32_bf16(af, wf1[1][kt], acc1[1], 0,0,0);
        }
        #pragma unroll
        for(int nt=0;nt<2;nt++){
            #pragma unroll
            for(int r=0;r<4;r++)
                y1buf[(quad*4+r)*YS + wave*32 + nt*16 + lc] = f2bf(fmaxf(acc1[nt][r] + be1v[nt], 0.f));
        }
        __syncthreads();
        f32x4 acc2[2];
        acc2[0] = (f32x4){0.f,0.f,0.f,0.f}; acc2[1] = (f32x4){0.f,0.f,0.f,0.f};
        #pragma unroll
        for(int kt=0;kt<4;kt++){
            bf16x8 af = *(const bf16x8*)&y1buf[lc*YS + kt*32 + quad*8];
            acc2[0] = __builtin_amdgcn_mfma_f32_16x16x32_bf16(af, wf2[0][kt], acc2[0], 0,0,0);
            acc2[1] = __builtin_amdgcn_mfma_f32_16x16x32_bf16(af, wf2[1][kt], acc2[1], 0,0,0);
        }
        float beta = sbeta[kk-1];
        float c1 = beta / sqrtf(1.f - sabar[kk-1]);
        float c2 = 1.f / sqrtf(1.f - beta);
        float sb = sqrtf(beta);
        #pragma unroll
        for(int nt=0;nt<2;nt++){
            int n = wave*32 + nt*16 + lc;
            #pragma unroll
            for(int r=0;r<4;r++){
                int m = quad*4 + r;
                float e = acc2[nt][r] + be2v[nt];
                float z = zbuf[m*ZS + n];
                float mean = (z - c1*e) * c2;
                float nz = noise[((size_t)s*NROW + row0 + m)*E_ + n];
                float znew = (kk > 1) ? (mean + sb*nz) : mean;
                zbuf[m*ZS + n] = znew * mrow[m];
            }
        }
        __syncthreads();
    }
    {
        int row = t >> 4, c0 = (t & 15) * 16;
        if(c0 < 128){
            #pragma unroll
            for(int i=0;i<16;i++)
                vsyn[(size_t)(row0+row)*E_ + c0 + i] = zbuf[row*ZS + c0 + i];
        }
    }
}

// ---------------------------------------------------------------- loss finalize (sums 512 partials + mask)
__global__ void k_finalize(const float* __restrict__ partial, const float* __restrict__ vmask, float* __restrict__ out){
    __shared__ float rb[4], rl[4];
    int t = threadIdx.x;
    float s = 0.f;
    for(int i=t;i<NROW;i+=256) s += vmask[i];
    float ls = 0.f;
    for(int i=t;i<512;i+=256) ls += partial[i];
    #pragma unroll
    for(int off=32;off;off>>=1){ s += __shfl_down(s, off); ls += __shfl_down(ls, off); }
    if((t & 63) == 0){ rb[t >> 6] = s; rl[t >> 6] = ls; }
    __syncthreads();
    if(t == 0){
        float denom = rb[0]+rb[1]+rb[2]+rb[3];
        if(denom < 1.f) denom = 1.f;
        out[256] = (rl[0]+rl[1]+rl[2]+rl[3]) / denom;
    }
}

extern "C" void kernel_launch(void* const* d_in, const int* in_sizes, int n_in,
                              void* d_out, int out_size, void* d_ws, size_t ws_size,
                              hipStream_t stream){
    const float* px    = (const float*)d_in[0];
    const float* vmask = (const float*)d_in[1];
    const int*   bins  = (const int*)d_in[2];
    const int*   tdiff = (const int*)d_in[3];
    const float* eps   = (const float*)d_in[4];
    const float* z0    = (const float*)d_in[5];
    const float* noise = (const float*)d_in[6];
    const float* Wv    = (const float*)d_in[7];
    const float* bemb  = (const float*)d_in[8];
    const float* Wih   = (const float*)d_in[9];
    const float* Whh   = (const float*)d_in[10];
    const float* bih   = (const float*)d_in[11];
    const float* bhh   = (const float*)d_in[12];
    const float* Wcls  = (const float*)d_in[13];
    const float* bcls  = (const float*)d_in[14];
    const float* Wproj = (const float*)d_in[15];
    const float* temb  = (const float*)d_in[16];
    const float* Wf    = (const float*)d_in[17];
    const float* bfu   = (const float*)d_in[18];
    const float* We1   = (const float*)d_in[19];
    const float* be1   = (const float*)d_in[20];
    const float* We2   = (const float*)d_in[21];
    const float* be2   = (const float*)d_in[22];
    float* out = (float*)d_out;

    float* ws      = (float*)d_ws;
    float* WT      = ws;
    float* v       = ws + 1048576;
    float* xg      = ws + 2097152;
    float* h       = ws + 6291456;
    float* hp      = ws + 7340032;
    float* vsyn    = ws + 8388608;
    float* partial = ws + 9437184;   // 512 floats

    hipLaunchKernelGGL(k_transpose_wv, dim3(V_/16), dim3(256), 0, stream, Wv, WT);
    hipLaunchKernelGGL(k_visit_embed, dim3(NROW), dim3(256), 0, stream, px, vmask, bins, bemb, WT, v);
    hipLaunchKernelGGL(k_gemm_xg, dim3(NROW/16), dim3(256), 0, stream, v, Wih, bih, bhh, xg);
    hipLaunchKernelGGL(k_lstm_mfma, dim3(B_/16), dim3(512), 0, stream, xg, Whh, vmask, h);
    hipLaunchKernelGGL(k_logits, dim3(B_), dim3(64), 0, stream, h, vmask, Wcls, bcls, out);
    hipLaunchKernelGGL(k_hp, dim3(NROW/16), dim3(256), 0, stream, h, Wproj, vmask, hp);
    hipLaunchKernelGGL(k_diff_loss_mfma, dim3(NROW/16), dim3(256), 0, stream,
                       v, hp, eps, tdiff, vmask, temb, Wf, bfu, We1, be1, We2, be2, partial);
    hipLaunchKernelGGL(k_reverse_mfma, dim3(NROW/16), dim3(256), 0, stream,
                       hp, z0, noise, vmask, temb, Wf, bfu, We1, be1, We2, be2, vsyn);
    hipLaunchKernelGGL(k_gemm_xg, dim3(NROW/16), dim3(256), 0, stream, vsyn, Wih, bih, bhh, xg);
    hipLaunchKernelGGL(k_lstm_mfma, dim3(B_/16), dim3(512), 0, stream, xg, Whh, vmask, h);
    hipLaunchKernelGGL(k_logits, dim3(B_), dim3(64), 0, stream, h, vmask, Wcls, bcls, out + 128);
    hipLaunchKernelGGL(k_finalize, dim3(1), dim3(256), 0, stream, partial, vmask, out);
}

// Round 7
// 817.767 us; speedup vs baseline: 2.2961x; 1.0133x over previous
//
#include <hip/hip_runtime.h>

#define B_ 128
#define L_ 64
#define V_ 8192
#define E_ 128
#define H_ 128
#define G4_ 512
#define NROW (B_*L_)
#define HSTRIDE 136
#define AS 136
#define XS 264
#define YS 136
#define ZS 132

typedef unsigned short u16;
typedef __attribute__((ext_vector_type(8))) short bf16x8;
typedef __attribute__((ext_vector_type(4))) float f32x4;

__device__ __forceinline__ float sigm(float x){ return 1.f/(1.f + __expf(-x)); }
__device__ __forceinline__ float ftanh(float x){ float e = __expf(2.f*x); return 1.f - 2.f/(e + 1.f); }
__device__ __forceinline__ u16 f2bf(float f){
    union { unsigned int i; float f; } x; x.f = f;
    unsigned int r = x.i + 0x7fff + ((x.i >> 16) & 1);
    return (u16)(r >> 16);
}
// raw barrier: LDS-only sync, no vmcnt drain
#define LBAR() asm volatile("s_waitcnt lgkmcnt(0)\ns_barrier" ::: "memory")

__device__ __forceinline__ bf16x8 pack8(const float* p){
    const float4* q = (const float4*)p;
    float4 a = q[0], b = q[1];
    bf16x8 f;
    f[0]=(short)f2bf(a.x); f[1]=(short)f2bf(a.y); f[2]=(short)f2bf(a.z); f[3]=(short)f2bf(a.w);
    f[4]=(short)f2bf(b.x); f[5]=(short)f2bf(b.y); f[6]=(short)f2bf(b.z); f[7]=(short)f2bf(b.w);
    return f;
}

// ---------------------------------------------------------------- transpose W_visit [E,V] -> WT [V,E]
__global__ __launch_bounds__(256) void k_transpose_wv(const float* __restrict__ Wv, float* __restrict__ WT){
    __shared__ float tile[16][129];
    int v0 = blockIdx.x * 16;
    int t = threadIdx.x;
    #pragma unroll
    for(int i=0;i<8;i++){
        int idx = i*256 + t; int e = idx >> 4; int vv = idx & 15;
        tile[vv][e] = Wv[(size_t)e*V_ + v0 + vv];
    }
    __syncthreads();
    #pragma unroll
    for(int i=0;i<8;i++){
        int idx = i*256 + t; int vv = idx >> 7; int e = idx & 127;
        WT[(size_t)(v0+vv)*E_ + e] = tile[vv][e];
    }
}

// ---------------------------------------------------------------- v = (x @ Wv^T + bin_embed[delta]) * m
__global__ __launch_bounds__(256) void k_visit_embed(const float* __restrict__ px, const float* __restrict__ vmask,
                                                     const int* __restrict__ bins, const float* __restrict__ bemb,
                                                     const float* __restrict__ WT, float* __restrict__ v){
    __shared__ int idxs[512];
    __shared__ int cnt;
    __shared__ int dsh;
    __shared__ float msh;
    __shared__ float4 red[8][32];
    int row = blockIdx.x; int l = row & 63;
    int t = threadIdx.x;
    if(t==0){
        cnt = 0;
        float m = vmask[row];
        int d = 0;
        if(l > 0){ d = bins[row] - bins[row-1]; d = d < 0 ? 0 : (d > 513 ? 513 : d); }
        if(!(m > 0.f)) d = 0;
        dsh = d; msh = m;
    }
    __syncthreads();
    const uint4* xr4 = (const uint4*)(px + (size_t)row * V_);
    for(int i=t;i<2048;i+=256){
        uint4 u = xr4[i];
        unsigned int w[4] = {u.x,u.y,u.z,u.w};
        #pragma unroll
        for(int j=0;j<4;j++){
            if(w[j]){ int p = atomicAdd(&cnt,1); if(p<512) idxs[p] = i*4 + j; }
        }
    }
    __syncthreads();
    int n = cnt; if(n > 512) n = 512;
    int eq = t & 31, jg = t >> 5;
    float4 a4 = {0.f,0.f,0.f,0.f};
    for(int j=jg;j<n;j+=8){
        const float4* wr = (const float4*)(WT + (size_t)idxs[j]*E_);
        float4 wv = wr[eq];
        a4.x += wv.x; a4.y += wv.y; a4.z += wv.z; a4.w += wv.w;
    }
    red[jg][eq] = a4;
    __syncthreads();
    if(t < 32){
        float4 s = red[0][t];
        #pragma unroll
        for(int g=1;g<8;g++){
            float4 r = red[g][t];
            s.x += r.x; s.y += r.y; s.z += r.z; s.w += r.w;
        }
        const float4* bp = (const float4*)(bemb + dsh*E_);
        float4 bv = bp[t];
        float m = msh;
        float4 o;
        o.x = (s.x + bv.x)*m; o.y = (s.y + bv.y)*m; o.z = (s.z + bv.z)*m; o.w = (s.w + bv.w)*m;
        ((float4*)(v + (size_t)row*E_))[t] = o;
    }
}

// ---------------------------------------------------------------- xg = A @ W_ih^T + b_ih + b_hh (MFMA, pass 1 from v)
__global__ __launch_bounds__(256,2) void k_gemm_xg(const float* __restrict__ A, const float* __restrict__ Wih,
                                                   const float* __restrict__ bih, const float* __restrict__ bhh,
                                                   float* __restrict__ xg){
    __shared__ __align__(16) u16 abuf[16*AS];
    int t = threadIdx.x, wave = t >> 6, lane = t & 63, quad = lane >> 4, lc = lane & 15;
    int row0 = blockIdx.x * 16;
    #pragma unroll
    for(int i=0;i<8;i++){
        int flat = i*256 + t; int r = flat >> 7, e = flat & 127;
        abuf[r*AS + e] = f2bf(A[(size_t)(row0+r)*E_ + e]);
    }
    bf16x8 wfr[8][4]; float bb[8];
    #pragma unroll
    for(int nt=0;nt<8;nt++){
        int n = wave*128 + nt*16 + lc;
        bb[nt] = bih[n] + bhh[n];
        const float* wr = Wih + (size_t)n*E_ + quad*8;
        #pragma unroll
        for(int kt=0;kt<4;kt++) wfr[nt][kt] = pack8(wr + kt*32);
    }
    __syncthreads();
    f32x4 acc[8];
    #pragma unroll
    for(int nt=0;nt<8;nt++) acc[nt] = (f32x4){0.f,0.f,0.f,0.f};
    #pragma unroll
    for(int kt=0;kt<4;kt++){
        bf16x8 af = *(const bf16x8*)&abuf[lc*AS + kt*32 + quad*8];
        #pragma unroll
        for(int nt=0;nt<8;nt++)
            acc[nt] = __builtin_amdgcn_mfma_f32_16x16x32_bf16(af, wfr[nt][kt], acc[nt], 0,0,0);
    }
    #pragma unroll
    for(int nt=0;nt<8;nt++){
        int n = wave*128 + nt*16 + lc;
        #pragma unroll
        for(int r=0;r<4;r++)
            xg[(size_t)(row0 + quad*4 + r)*G4_ + n] = acc[nt][r] + bb[nt];
    }
}

// ---------------------------------------------------------------- LSTM fused: recurrence + hp (pass1) + logits
__device__ __forceinline__ void lstm_step(int l, const float* pxg, float* hp_out, bool dohp,
        const u16* bufr, u16* bufw, const bf16x8 (&bf)[4][4], const bf16x8 (&wp)[4],
        float (&xcur)[4][4], float (&xnxt)[4][4], float (&c4)[4], float (&lg4)[4],
        const int (&len4)[4], float wcv,
        const float* vmsh, int lc, int quad, int wave, int b0){
    // prefetch next step's xg first (longest latency)
    if(l+1 < 64){
        #pragma unroll
        for(int gate=0;gate<4;gate++){
            #pragma unroll
            for(int r=0;r<4;r++)
                xnxt[gate][r] = pxg[(size_t)r*64*G4_ + (size_t)(l+1)*G4_ + gate*128];
        }
    }
    bf16x8 af[4];
    #pragma unroll
    for(int kt=0;kt<4;kt++)
        af[kt] = *(const bf16x8*)&bufr[lc*HSTRIDE + kt*32 + quad*8];
    f32x4 acc[4], acch;
    #pragma unroll
    for(int a=0;a<4;a++) acc[a] = (f32x4){0.f,0.f,0.f,0.f};
    acch = (f32x4){0.f,0.f,0.f,0.f};
    #pragma unroll
    for(int kt=0;kt<4;kt++){
        #pragma unroll
        for(int a=0;a<4;a++)
            acc[a] = __builtin_amdgcn_mfma_f32_16x16x32_bf16(af[kt], bf[a][kt], acc[a], 0,0,0);
        acch = __builtin_amdgcn_mfma_f32_16x16x32_bf16(af[kt], wp[kt], acch, 0,0,0);
    }
    if(dohp){
        // hp[b, l] = h_{l-1} @ Wproj^T * m[b,l]  (af IS h_{l-1}; af=0 at l=0 -> hp=0)
        #pragma unroll
        for(int r=0;r<4;r++){
            float m = vmsh[(quad*4+r)*64 + l];
            int grow = (b0 + quad*4 + r)*64 + l;
            hp_out[(size_t)grow*E_ + wave*16 + lc] = acch[r] * m;
        }
    }
    #pragma unroll
    for(int r=0;r<4;r++){
        float gi = acc[0][r] + xcur[0][r];
        float gf = acc[1][r] + xcur[1][r];
        float gg = acc[2][r] + xcur[2][r];
        float go = acc[3][r] + xcur[3][r];
        float c  = sigm(gf)*c4[r] + sigm(gi)*ftanh(gg);
        float h  = sigm(go)*ftanh(c);
        c4[r] = c;
        bufw[(quad*4+r)*HSTRIDE + wave*16 + lc] = f2bf(h);
        if(l == len4[r]-1) lg4[r] += h * wcv;   // h unmasked == masked at valid pos
    }
    LBAR();
}

__global__ __launch_bounds__(512,2) void k_lstm_fused(const float* __restrict__ xg, const float* __restrict__ Whh,
        const float* __restrict__ Wproj, const float* __restrict__ Wcls, const float* __restrict__ bcls,
        const float* __restrict__ vmask, float* __restrict__ hp_out, float* __restrict__ logits_out){
    __shared__ u16 hbuf[2][16*HSTRIDE];
    __shared__ float vmsh[16*64];
    __shared__ int lensh[16];
    __shared__ float lgsh[16][132];
    int t = threadIdx.x;
    int wave = t >> 6, lane = t & 63;
    int quad = lane >> 4, lc = lane & 15;
    int b0 = blockIdx.x * 16;
    bool dohp = (hp_out != nullptr);

    for(int i=t;i<16*HSTRIDE;i+=512) hbuf[0][i] = 0;
    for(int i=t;i<1024;i+=512) vmsh[i] = vmask[b0*64 + i];
    __syncthreads();
    if(t < 16){
        int s = 0;
        #pragma unroll
        for(int i=0;i<64;i++) s += (vmsh[t*64 + i] > 0.f) ? 1 : 0;
        lensh[t] = s < 1 ? 1 : s;
    }

    int cw = wave*16 + lc;
    bf16x8 bf[4][4];
    #pragma unroll
    for(int gate=0;gate<4;gate++){
        int n = gate*128 + cw;
        const float* wr = Whh + (size_t)n*H_ + quad*8;
        #pragma unroll
        for(int kt=0;kt<4;kt++) bf[gate][kt] = pack8(wr + kt*32);
    }
    bf16x8 wp[4];
    {
        const float* wr = Wproj + (size_t)cw*H_ + quad*8;
        #pragma unroll
        for(int kt=0;kt<4;kt++) wp[kt] = pack8(wr + kt*32);
    }
    float wcv = Wcls[cw];

    float c4[4] = {0.f,0.f,0.f,0.f};
    float lg4[4] = {0.f,0.f,0.f,0.f};

    const float* pxg = xg + ((size_t)(b0 + quad*4))*64*G4_ + cw;

    float xgv0[4][4], xgv1[4][4];
    #pragma unroll
    for(int gate=0;gate<4;gate++){
        #pragma unroll
        for(int r=0;r<4;r++)
            xgv0[gate][r] = pxg[(size_t)r*64*G4_ + gate*128];
    }
    __syncthreads();
    int len4[4];
    #pragma unroll
    for(int r=0;r<4;r++) len4[r] = lensh[quad*4 + r];

    for(int lb=0;lb<64;lb+=2){
        lstm_step(lb,   pxg, hp_out, dohp, hbuf[0], hbuf[1], bf, wp, xgv0, xgv1, c4, lg4, len4, wcv, vmsh, lc, quad, wave, b0);
        lstm_step(lb+1, pxg, hp_out, dohp, hbuf[1], hbuf[0], bf, wp, xgv1, xgv0, c4, lg4, len4, wcv, vmsh, lc, quad, wave, b0);
    }
    // logits reduce: lgsh[row][col]
    #pragma unroll
    for(int r=0;r<4;r++) lgsh[quad*4+r][cw] = lg4[r];
    __syncthreads();
    {
        int row = t >> 5, l32 = t & 31;
        float s = lgsh[row][l32] + lgsh[row][l32+32] + lgsh[row][l32+64] + lgsh[row][l32+96];
        s += __shfl_down(s, 16, 32);
        s += __shfl_down(s, 8, 32);
        s += __shfl_down(s, 4, 32);
        s += __shfl_down(s, 2, 32);
        s += __shfl_down(s, 1, 32);
        if(l32 == 0) logits_out[b0 + row] = s + bcls[0];
    }
}

// ---------------------------------------------------------------- fused: diff_loss + reverse diffusion + xg2 GEMM
__global__ __launch_bounds__(256,2) void k_drg(const float* __restrict__ v, const float* __restrict__ hp,
        const float* __restrict__ eps, const int* __restrict__ tdiff, const float* __restrict__ vmask,
        const float* __restrict__ z0, const float* __restrict__ noise, const float* __restrict__ temb,
        const float* __restrict__ Wf, const float* __restrict__ bfu,
        const float* __restrict__ We1, const float* __restrict__ be1,
        const float* __restrict__ We2, const float* __restrict__ be2,
        const float* __restrict__ Wih, const float* __restrict__ bih, const float* __restrict__ bhh,
        float* __restrict__ partial, float* __restrict__ xg2){
    __shared__ float zbuf[16*ZS], hpbuf[16*ZS];
    __shared__ __align__(16) u16 xbuf[16*XS];
    __shared__ __align__(16) u16 y1buf[16*YS];
    __shared__ float wfsh[512];
    __shared__ float ssh[16][2], hpd[16][2];
    __shared__ float mrow[16]; __shared__ int trow[16];
    __shared__ float sbeta[10], sabar[10];
    __shared__ float rb[4];
    int row0 = blockIdx.x * 16; int t = threadIdx.x;
    int wave = t >> 6, lane = t & 63, quad = lane >> 4, lc = lane & 15;

    if(t==0){
        float p = 1.f;
        for(int k=0;k<10;k++){ float b = 1e-4f + (0.02f - 1e-4f)*k/9.f; sbeta[k] = b; p *= (1.f - b); sabar[k] = p; }
    }
    if(t < 16){
        int row = row0 + t; float m = vmask[row];
        mrow[t] = m; trow[t] = (m > 0.f) ? tdiff[row >> 6] : 1;
    }
    for(int i=t;i<512;i+=256) wfsh[i] = Wf[i];
    __syncthreads();
    // z_t (diffusion-loss forward sample) and hp into LDS
    #pragma unroll
    for(int i=0;i<8;i++){
        int flat = i*256 + t; int r = flat >> 7; int e = flat & 127; int row = row0 + r;
        float ab = sabar[trow[r]-1];
        zbuf[r*ZS + e] = (sqrtf(ab)*v[(size_t)row*E_ + e] + sqrtf(1.f - ab)*eps[(size_t)row*E_ + e]) * mrow[r];
        hpbuf[r*ZS + e] = hp[(size_t)row*E_ + e];
    }
    bf16x8 wf1[2][8], wf2[2][4];
    float be1v[2], be2v[2];
    #pragma unroll
    for(int nt=0;nt<2;nt++){
        int n = wave*32 + nt*16 + lc;
        be1v[nt] = be1[n]; be2v[nt] = be2[n];
        const float* w1 = We1 + (size_t)n*256 + quad*8;
        #pragma unroll
        for(int kt=0;kt<8;kt++) wf1[nt][kt] = pack8(w1 + kt*32);
        const float* w2 = We2 + (size_t)n*128 + quad*8;
        #pragma unroll
        for(int kt=0;kt<4;kt++) wf2[nt][kt] = pack8(w2 + kt*32);
    }
    __syncthreads();
    // hp·Wf[:,128:256]+bfu (reused by both diff and all 10 reverse steps)
    {
        int row = t >> 4, k = (t >> 3) & 1, sub = t & 7;
        float p = 0.f;
        #pragma unroll
        for(int i=0;i<16;i++)
            p += hpbuf[row*ZS + sub*16 + i] * wfsh[k*256 + 128 + sub*16 + i];
        p += __shfl_down(p,4); p += __shfl_down(p,2); p += __shfl_down(p,1);
        if(sub == 0) hpd[row][k] = p + bfu[k];
    }
    __syncthreads();

    // ---------- 11 fuse_eps evaluations: s=0 -> diff loss on z_t; s=1..10 -> reverse steps
    for(int s=0;s<11;s++){
        int kk = 10 - (s - 1);          // reverse step index for s>=1
        {
            int row = t >> 4, k = (t >> 3) & 1, sub = t & 7;
            float q = 0.f;
            #pragma unroll
            for(int i=0;i<16;i++)
                q += zbuf[row*ZS + sub*16 + i] * wfsh[k*256 + sub*16 + i];
            q += __shfl_down(q,4); q += __shfl_down(q,2); q += __shfl_down(q,1);
            if(sub == 0) ssh[row][k] = q + hpd[row][k];
        }
        __syncthreads();
        {
            int row = t >> 4, c0 = (t & 15) * 16;
            float s0 = ssh[row][0], s1 = ssh[row][1];
            float a0 = 1.f/(1.f + __expf(s1 - s0)), a1 = 1.f - a0;
            int tt = (s == 0) ? trow[row] : ((mrow[row] > 0.f) ? kk : 1);
            #pragma unroll
            for(int i=0;i<16;i++){
                int c = c0 + i;
                float val = (c < 128) ? (a0*zbuf[row*ZS + c] + a1*hpbuf[row*ZS + c])
                                      : temb[tt*E_ + (c - 128)];
                xbuf[row*XS + c] = f2bf(val);
            }
        }
        __syncthreads();
        f32x4 acc1[2];
        acc1[0] = (f32x4){0.f,0.f,0.f,0.f}; acc1[1] = (f32x4){0.f,0.f,0.f,0.f};
        #pragma unroll
        for(int kt=0;kt<8;kt++){
            bf16x8 af = *(const bf16x8*)&xbuf[lc*XS + kt*32 + quad*8];
            acc1[0] = __builtin_amdgcn_mfma_f32_16x16x32_bf16(af, wf1[0][kt], acc1[0], 0,0,0);
            acc1[1] = __builtin_amdgcn_mfma_f32_16x16x32_bf16(af, wf1[1][kt], acc1[1], 0,0,0);
        }
        #pragma unroll
        for(int nt=0;nt<2;nt++){
            #pragma unroll
            for(int r=0;r<4;r++)
                y1buf[(quad*4+r)*YS + wave*32 + nt*16 + lc] = f2bf(fmaxf(acc1[nt][r] + be1v[nt], 0.f));
        }
        __syncthreads();
        f32x4 acc2[2];
        acc2[0] = (f32x4){0.f,0.f,0.f,0.f}; acc2[1] = (f32x4){0.f,0.f,0.f,0.f};
        #pragma unroll
        for(int kt=0;kt<4;kt++){
            bf16x8 af = *(const bf16x8*)&y1buf[lc*YS + kt*32 + quad*8];
            acc2[0] = __builtin_amdgcn_mfma_f32_16x16x32_bf16(af, wf2[0][kt], acc2[0], 0,0,0);
            acc2[1] = __builtin_amdgcn_mfma_f32_16x16x32_bf16(af, wf2[1][kt], acc2[1], 0,0,0);
        }
        if(s == 0){
            // diffusion loss partial; then load z0 for the reverse chain
            float lp = 0.f;
            #pragma unroll
            for(int nt=0;nt<2;nt++){
                int n = wave*32 + nt*16 + lc;
                #pragma unroll
                for(int r=0;r<4;r++){
                    int m = quad*4 + r;
                    float d = (acc2[nt][r] + be2v[nt]) - eps[(size_t)(row0+m)*E_ + n];
                    lp += d*d*mrow[m];
                }
            }
            #pragma unroll
            for(int off=32;off;off>>=1) lp += __shfl_down(lp, off);
            if(lane == 0) rb[wave] = lp;
            __syncthreads();
            if(t == 0) partial[blockIdx.x] = rb[0]+rb[1]+rb[2]+rb[3];
            #pragma unroll
            for(int i=0;i<8;i++){
                int flat = i*256 + t; int r = flat >> 7; int e = flat & 127;
                zbuf[r*ZS + e] = z0[(size_t)(row0+r)*E_ + e];
            }
            __syncthreads();
        } else {
            float beta = sbeta[kk-1];
            float c1 = beta / sqrtf(1.f - sabar[kk-1]);
            float c2 = 1.f / sqrtf(1.f - beta);
            float sb = sqrtf(beta);
            #pragma unroll
            for(int nt=0;nt<2;nt++){
                int n = wave*32 + nt*16 + lc;
                #pragma unroll
                for(int r=0;r<4;r++){
                    int m = quad*4 + r;
                    float e = acc2[nt][r] + be2v[nt];
                    float z = zbuf[m*ZS + n];
                    float mean = (z - c1*e) * c2;
                    float nz = noise[((size_t)(s-1)*NROW + row0 + m)*E_ + n];
                    float znew = (kk > 1) ? (mean + sb*nz) : mean;
                    zbuf[m*ZS + n] = znew * mrow[m];
                }
            }
            __syncthreads();
        }
    }
    // ---------- xg2 = v_syn @ Wih^T + bih + bhh (v_syn = final zbuf)
    {
        int row = t >> 4, c0 = (t & 15) * 8;
        #pragma unroll
        for(int i=0;i<8;i++)
            xbuf[row*XS + c0 + i] = f2bf(zbuf[row*ZS + c0 + i]);
    }
    __syncthreads();
    bf16x8 wg[8][4]; float bb[8];
    #pragma unroll
    for(int nt=0;nt<8;nt++){
        int n = wave*128 + nt*16 + lc;
        bb[nt] = bih[n] + bhh[n];
        const float* wr = Wih + (size_t)n*E_ + quad*8;
        #pragma unroll
        for(int kt=0;kt<4;kt++) wg[nt][kt] = pack8(wr + kt*32);
    }
    f32x4 ac[8];
    #pragma unroll
    for(int nt=0;nt<8;nt++) ac[nt] = (f32x4){0.f,0.f,0.f,0.f};
    #pragma unroll
    for(int kt=0;kt<4;kt++){
        bf16x8 af = *(const bf16x8*)&xbuf[lc*XS + kt*32 + quad*8];
        #pragma unroll
        for(int nt=0;nt<8;nt++)
            ac[nt] = __builtin_amdgcn_mfma_f32_16x16x32_bf16(af, wg[nt][kt], ac[nt], 0,0,0);
    }
    #pragma unroll
    for(int nt=0;nt<8;nt++){
        int n = wave*128 + nt*16 + lc;
        #pragma unroll
        for(int r=0;r<4;r++)
            xg2[(size_t)(row0 + quad*4 + r)*G4_ + n] = ac[nt][r] + bb[nt];
    }
}

// ---------------------------------------------------------------- loss finalize (sums 512 partials + mask)
__global__ void k_finalize(const float* __restrict__ partial, const float* __restrict__ vmask, float* __restrict__ out){
    __shared__ float rb[4], rl[4];
    int t = threadIdx.x;
    float s = 0.f;
    for(int i=t;i<NROW;i+=256) s += vmask[i];
    float ls = 0.f;
    for(int i=t;i<512;i+=256) ls += partial[i];
    #pragma unroll
    for(int off=32;off;off>>=1){ s += __shfl_down(s, off); ls += __shfl_down(ls, off); }
    if((t & 63) == 0){ rb[t >> 6] = s; rl[t >> 6] = ls; }
    __syncthreads();
    if(t == 0){
        float denom = rb[0]+rb[1]+rb[2]+rb[3];
        if(denom < 1.f) denom = 1.f;
        out[256] = (rl[0]+rl[1]+rl[2]+rl[3]) / denom;
    }
}

extern "C" void kernel_launch(void* const* d_in, const int* in_sizes, int n_in,
                              void* d_out, int out_size, void* d_ws, size_t ws_size,
                              hipStream_t stream){
    const float* px    = (const float*)d_in[0];
    const float* vmask = (const float*)d_in[1];
    const int*   bins  = (const int*)d_in[2];
    const int*   tdiff = (const int*)d_in[3];
    const float* eps   = (const float*)d_in[4];
    const float* z0    = (const float*)d_in[5];
    const float* noise = (const float*)d_in[6];
    const float* Wv    = (const float*)d_in[7];
    const float* bemb  = (const float*)d_in[8];
    const float* Wih   = (const float*)d_in[9];
    const float* Whh   = (const float*)d_in[10];
    const float* bih   = (const float*)d_in[11];
    const float* bhh   = (const float*)d_in[12];
    const float* Wcls  = (const float*)d_in[13];
    const float* bcls  = (const float*)d_in[14];
    const float* Wproj = (const float*)d_in[15];
    const float* temb  = (const float*)d_in[16];
    const float* Wf    = (const float*)d_in[17];
    const float* bfu   = (const float*)d_in[18];
    const float* We1   = (const float*)d_in[19];
    const float* be1   = (const float*)d_in[20];
    const float* We2   = (const float*)d_in[21];
    const float* be2   = (const float*)d_in[22];
    float* out = (float*)d_out;

    float* ws      = (float*)d_ws;
    float* WT      = ws;                 // 1,048,576
    float* v       = ws + 1048576;       // 1,048,576
    float* xg      = ws + 2097152;       // 4,194,304
    float* hp      = ws + 6291456;       // 1,048,576
    float* partial = ws + 7340032;       // 512

    hipLaunchKernelGGL(k_transpose_wv, dim3(V_/16), dim3(256), 0, stream, Wv, WT);
    hipLaunchKernelGGL(k_visit_embed, dim3(NROW), dim3(256), 0, stream, px, vmask, bins, bemb, WT, v);
    hipLaunchKernelGGL(k_gemm_xg, dim3(NROW/16), dim3(256), 0, stream, v, Wih, bih, bhh, xg);
    hipLaunchKernelGGL(k_lstm_fused, dim3(B_/16), dim3(512), 0, stream,
                       xg, Whh, Wproj, Wcls, bcls, vmask, hp, out);
    hipLaunchKernelGGL(k_drg, dim3(NROW/16), dim3(256), 0, stream,
                       v, hp, eps, tdiff, vmask, z0, noise, temb, Wf, bfu,
                       We1, be1, We2, be2, Wih, bih, bhh, partial, xg);
    hipLaunchKernelGGL(k_lstm_fused, dim3(B_/16), dim3(512), 0, stream,
                       xg, Whh, Wproj, Wcls, bcls, vmask, (float*)nullptr, out + 128);
    hipLaunchKernelGGL(k_finalize, dim3(1), dim3(256), 0, stream, partial, vmask, out);
}